// Round 6
// baseline (1857.918 us; speedup 1.0000x reference)
//
#include <hip/hip_runtime.h>
#include <stdint.h>
#include <math.h>

// MS_MSA fused pipeline:
//   compose_kernel : Weff[h][chain] = w1*w2*w3 composed 7x7 stencil (fp32, ws)
//   posemb_kernel  : x2 = x + dw2(gelu(dw1(x)+b1))+b2   (2-stage tile fusion)
//   qkv_fused      : INTERIOR tiles: composed-7x7 sweep, chains processed
//                    SEQUENTIALLY (unroll 1) so only 49 weights + 16 acc live
//                    at a time (~100 VGPR, no spill; r5's joint sweep spilled
//                    1.1GB/dispatch at 256 VGPR). Weights LDS->VGPR broadcast
//                    (no s_load in loop), iy fully unrolled per chain. K3s/Q3s
//                    separate LDS (no alias with live halo). Epilogue: Gram
//                    MFMA + reductions. q3/k3 never hit HBM.
//   chain3/kchain  : BORDER tiles only (92/512 positions) via exact 3-stage path.
//   attn/mbuild    : softmax + fold proj_w*blockdiag(attn) -> M
//   gemm           : out = v3 @ M_b^T + proj_b  (bf16 MFMA, fp32 out)
// ws: S0=x2, S1=v3 (2 x 64MiB) + smalls + Wc(4.7KB) — layout == verified r1.
// d_out scratch: [0,64MiB) q3 (border tiles only; dead before gemm).

using u16 = unsigned short;
using u32 = unsigned int;

typedef __bf16 bf16x8_t __attribute__((ext_vector_type(8)));
typedef float f32x4_t __attribute__((ext_vector_type(4)));

__device__ __forceinline__ float bf2f(u16 v) {
  u32 u = ((u32)v) << 16;
  return __builtin_bit_cast(float, u);
}
__device__ __forceinline__ u16 f2bf(float f) {
  u32 u = __builtin_bit_cast(u32, f);
  u32 r = u + 0x7fffu + ((u >> 16) & 1u);  // RNE (finite inputs)
  return (u16)(r >> 16);
}
__device__ __forceinline__ void unpack8(uint4 u, float f[8]) {
  f[0] = bf2f((u16)(u.x & 0xffffu)); f[1] = bf2f((u16)(u.x >> 16));
  f[2] = bf2f((u16)(u.y & 0xffffu)); f[3] = bf2f((u16)(u.y >> 16));
  f[4] = bf2f((u16)(u.z & 0xffffu)); f[5] = bf2f((u16)(u.z >> 16));
  f[6] = bf2f((u16)(u.w & 0xffffu)); f[7] = bf2f((u16)(u.w >> 16));
}
__device__ __forceinline__ uint4 pack8(const u16 o[8]) {
  uint4 v;
  v.x = (u32)o[0] | ((u32)o[1] << 16);
  v.y = (u32)o[2] | ((u32)o[3] << 16);
  v.z = (u32)o[4] | ((u32)o[5] << 16);
  v.w = (u32)o[6] | ((u32)o[7] << 16);
  return v;
}

// ---------------------------------------------------------------------------
// compose: Weff = w1 (*) w2 (*) w3 (kernel-array convolution; correlation
// offsets add). Wc[h][c][dy*7+dx], c: 0=q,1=k,2=v. 24 active threads.
__global__ __launch_bounds__(64) void compose_kernel(
    const float* __restrict__ qw1, const float* __restrict__ qw2,
    const float* __restrict__ qw3, const float* __restrict__ kw1,
    const float* __restrict__ kw2, const float* __restrict__ kw3,
    const float* __restrict__ vw1, const float* __restrict__ vw2,
    const float* __restrict__ vw3, float* __restrict__ Wc) {
  const int t = threadIdx.x;
  if (t >= 24) return;
  const int h = t / 3, c = t % 3;
  const float* w1 = (c == 0 ? qw1 : c == 1 ? kw1 : vw1) + h * 9;
  const float* w2 = (c == 0 ? qw2 : c == 1 ? kw2 : vw2) + h * 9;
  const float* w3 = (c == 0 ? qw3 : c == 1 ? kw3 : vw3) + h * 9;
  float w12[25];
  for (int i = 0; i < 25; ++i) w12[i] = 0.f;
  for (int ky = 0; ky < 3; ++ky)
    for (int kx = 0; kx < 3; ++kx)
      for (int ly = 0; ly < 3; ++ly)
        for (int lx = 0; lx < 3; ++lx)
          w12[(ky + ly) * 5 + kx + lx] += w2[ky * 3 + kx] * w1[ly * 3 + lx];
  float we[49];
  for (int i = 0; i < 49; ++i) we[i] = 0.f;
  for (int my = 0; my < 3; ++my)
    for (int mx = 0; mx < 3; ++mx)
      for (int ey = 0; ey < 5; ++ey)
        for (int ex = 0; ex < 5; ++ex)
          we[(my + ey) * 7 + mx + ex] += w3[my * 3 + mx] * w12[ey * 5 + ex];
  float* dst = Wc + (h * 3 + c) * 49;
  for (int i = 0; i < 49; ++i) dst[i] = we[i];
}

// ---------------------------------------------------------------------------
// posemb: 2-stage fused, per-channel weights, fp32 input, gelu, residual.
__global__ __launch_bounds__(256) void posemb_kernel(
    const float* __restrict__ xin, u16* __restrict__ x2,
    const float* __restrict__ w1g, const float* __restrict__ b1g,
    const float* __restrict__ w2g, const float* __restrict__ b2g) {
  const int t = threadIdx.x;
  const int o = t & 3;
  const int bz = blockIdx.z;
  const int cg = bz & 7;
  const int b = bz >> 3;
  const int x0 = blockIdx.x * 16;
  const int y0 = blockIdx.y * 8;
  const int c0 = cg * 32 + o * 8;

  __shared__ __align__(16) u16 Abuf[240 * 32];
  __shared__ __align__(16) u16 Bbuf[180 * 32];

  for (int i = t; i < 240 * 4; i += 256) {
    const int px = i >> 2, oo = i & 3;
    const int lx = px % 20, ly = px / 20;
    const int gx = x0 - 2 + lx, gy = y0 - 2 + ly;
    u16 ov[8];
    if (gx >= 0 && gx < 256 && gy >= 0 && gy < 256) {
      const float* p = xin + ((size_t)((b << 16) + (gy << 8) + gx)) * 256 + cg * 32 + oo * 8;
      const float4 r0 = *reinterpret_cast<const float4*>(p);
      const float4 r1 = *reinterpret_cast<const float4*>(p + 4);
      ov[0] = f2bf(r0.x); ov[1] = f2bf(r0.y); ov[2] = f2bf(r0.z); ov[3] = f2bf(r0.w);
      ov[4] = f2bf(r1.x); ov[5] = f2bf(r1.y); ov[6] = f2bf(r1.z); ov[7] = f2bf(r1.w);
    } else {
#pragma unroll
      for (int j = 0; j < 8; ++j) ov[j] = 0;
    }
    *reinterpret_cast<uint4*>(Abuf + px * 32 + oo * 8) = pack8(ov);
  }
  __syncthreads();

  {
    float w[72], bi[8];
#pragma unroll
    for (int j = 0; j < 8; ++j) {
#pragma unroll
      for (int k = 0; k < 9; ++k) w[j * 9 + k] = w1g[(c0 + j) * 9 + k];
      bi[j] = b1g[c0 + j];
    }
    for (int i = t; i < 180 * 4; i += 256) {
      const int px = i >> 2;
      const int sx = px % 18, sy = px / 18;
      const int gx = x0 - 1 + sx, gy = y0 - 1 + sy;
      const bool inb = (gx >= 0 && gx < 256 && gy >= 0 && gy < 256);
      float a[8];
#pragma unroll
      for (int j = 0; j < 8; ++j) a[j] = bi[j];
#pragma unroll
      for (int ky = 0; ky < 3; ++ky)
#pragma unroll
        for (int kx = 0; kx < 3; ++kx) {
          float f[8];
          unpack8(*reinterpret_cast<const uint4*>(
                      Abuf + ((sy + ky) * 20 + sx + kx) * 32 + o * 8), f);
#pragma unroll
          for (int j = 0; j < 8; ++j) a[j] = fmaf(w[j * 9 + ky * 3 + kx], f[j], a[j]);
        }
      u16 ov[8];
#pragma unroll
      for (int j = 0; j < 8; ++j) {
        const float g = 0.5f * a[j] * (1.0f + erff(a[j] * 0.70710678118654752f));
        ov[j] = inb ? f2bf(g) : (u16)0;
      }
      *reinterpret_cast<uint4*>(Bbuf + px * 32 + o * 8) = pack8(ov);
    }
  }
  __syncthreads();

  {
    float w[72], bi[8];
#pragma unroll
    for (int j = 0; j < 8; ++j) {
#pragma unroll
      for (int k = 0; k < 9; ++k) w[j * 9 + k] = w2g[(c0 + j) * 9 + k];
      bi[j] = b2g[c0 + j];
    }
    for (int i = t; i < 128 * 4; i += 256) {
      const int px = i >> 2;
      const int sx = px & 15, sy = px >> 4;
      float a[8];
#pragma unroll
      for (int j = 0; j < 8; ++j) a[j] = bi[j];
#pragma unroll
      for (int ky = 0; ky < 3; ++ky)
#pragma unroll
        for (int kx = 0; kx < 3; ++kx) {
          float f[8];
          unpack8(*reinterpret_cast<const uint4*>(
                      Bbuf + ((sy + ky) * 18 + sx + kx) * 32 + o * 8), f);
#pragma unroll
          for (int j = 0; j < 8; ++j) a[j] = fmaf(w[j * 9 + ky * 3 + kx], f[j], a[j]);
        }
      float xr[8];
      unpack8(*reinterpret_cast<const uint4*>(
                  Abuf + ((sy + 2) * 20 + sx + 2) * 32 + o * 8), xr);
      u16 ov[8];
#pragma unroll
      for (int j = 0; j < 8; ++j) ov[j] = f2bf(a[j] + xr[j]);
      u16* dst = x2 + ((size_t)((b << 16) + ((y0 + sy) << 8) + x0 + sx)) * 256 + cg * 32 + o * 8;
      *reinterpret_cast<uint4*>(dst) = pack8(ov);
    }
  }
}

// ---------------------------------------------------------------------------
// qkv_fused: interior tiles only (bx 1..14, by 1..30 of the 16x8 tiling).
// One 22x14 halo load; per-chain composed-7x7 sweep (c looped with unroll 1
// to cap live registers at ~49 W + 16 acc). Weights LDS->VGPR broadcast.
// K3s/Q3s separate LDS arrays (halo stays live across all 3 sweeps).
// Thread: o=t&3 (8 ch), sx=(t>>2)&15, yg=t>>6 -> output rows yg*2, yg*2+1.
__global__ __launch_bounds__(256) void qkv_fused_kernel(
    const u16* __restrict__ x2, u16* __restrict__ v3out,
    const float* __restrict__ Wc, float* __restrict__ G,
    float* __restrict__ sqq, float* __restrict__ sqk,
    float* __restrict__ vsum) {
  const int t = threadIdx.x;
  const int o = t & 3;
  const int sx = (t >> 2) & 15;
  const int yg = t >> 6;
  const int bz = blockIdx.z;
  const int h = bz & 7;
  const int b = bz >> 3;
  const int x0 = (blockIdx.x + 1) * 16;
  const int y0 = (blockIdx.y + 1) * 8;

  __shared__ __align__(16) u16 Abuf[308 * 32];  // halo 22x14 (live all sweeps)
  __shared__ __align__(16) u16 K3s[32 * 132];
  __shared__ __align__(16) u16 Q3s[32 * 132];
  __shared__ float Wl[147];
  __shared__ float rbuf[96];
  if (t < 96) rbuf[t] = 0.f;
  if (t >= 96 && t < 96 + 147) Wl[t - 96] = Wc[h * 147 + (t - 96)];

  // P0: load halo (interior -> no bounds checks)
  for (int i = t; i < 308 * 4; i += 256) {
    const int px = i >> 2, oo = i & 3;
    const int lx = px % 22, ly = px / 22;
    const int gx = x0 - 3 + lx, gy = y0 - 3 + ly;
    *reinterpret_cast<uint4*>(Abuf + px * 32 + oo * 8) =
        *reinterpret_cast<const uint4*>(
            x2 + ((size_t)((b << 16) + (gy << 8) + gx)) * 256 + h * 32 + oo * 8);
  }
  __syncthreads();

  const int ty0 = yg * 2;
  const u16* Arow0 = Abuf + (ty0 * 22 + sx) * 32 + o * 8;
  const int px0 = ty0 * 16 + sx;
  const int px1 = (ty0 + 1) * 16 + sx;

  // Chains SEQUENTIAL: only one 49-weight set + 16 acc live at a time.
#pragma unroll 1
  for (int c = 0; c < 3; ++c) {
    float W[49];
#pragma unroll
    for (int k = 0; k < 49; ++k) W[k] = Wl[c * 49 + k];
    float a0[8], a1[8];
#pragma unroll
    for (int j = 0; j < 8; ++j) { a0[j] = 0.f; a1[j] = 0.f; }

    // Fully unrolled per chain: iy 0..7; ry=0 uses iy=dy (0..6),
    // ry=1 uses iy=dy+1 (1..7). All weight indices compile-time.
#pragma unroll
    for (int iy = 0; iy <= 7; ++iy) {
      const u16* Ar = Arow0 + iy * (22 * 32);
#pragma unroll
      for (int jx = 0; jx < 7; ++jx) {
        float f[8];
        unpack8(*reinterpret_cast<const uint4*>(Ar + jx * 32), f);
        if (iy < 7) {
          const float w = W[iy * 7 + jx];
#pragma unroll
          for (int j = 0; j < 8; ++j) a0[j] = fmaf(w, f[j], a0[j]);
        }
        if (iy > 0) {
          const float w = W[(iy - 1) * 7 + jx];
#pragma unroll
          for (int j = 0; j < 8; ++j) a1[j] = fmaf(w, f[j], a1[j]);
        }
      }
    }

    // per-chain epilogue
    u16 b0[8], b1[8];
    float rs[8];
#pragma unroll
    for (int j = 0; j < 8; ++j) {
      b0[j] = f2bf(a0[j]);
      b1[j] = f2bf(a1[j]);
      const float f0 = bf2f(b0[j]);
      const float f1 = bf2f(b1[j]);
      rs[j] = (c == 2) ? (f0 + f1) : fmaf(f0, f0, f1 * f1);
    }
    if (c == 0) {
#pragma unroll
      for (int j = 0; j < 8; ++j) {
        Q3s[(o * 8 + j) * 132 + px0] = b0[j];
        Q3s[(o * 8 + j) * 132 + px1] = b1[j];
        atomicAdd(&rbuf[o * 8 + j], rs[j]);
      }
    } else if (c == 1) {
#pragma unroll
      for (int j = 0; j < 8; ++j) {
        K3s[(o * 8 + j) * 132 + px0] = b0[j];
        K3s[(o * 8 + j) * 132 + px1] = b1[j];
        atomicAdd(&rbuf[32 + o * 8 + j], rs[j]);
      }
    } else {
      u16* d0p = v3out + ((size_t)((b << 16) + ((y0 + ty0) << 8) + x0 + sx)) * 256 + h * 32 + o * 8;
      u16* d1p = v3out + ((size_t)((b << 16) + ((y0 + ty0 + 1) << 8) + x0 + sx)) * 256 + h * 32 + o * 8;
      *reinterpret_cast<uint4*>(d0p) = pack8(b0);
      *reinterpret_cast<uint4*>(d1p) = pack8(b1);
#pragma unroll
      for (int j = 0; j < 8; ++j) atomicAdd(&rbuf[64 + o * 8 + j], rs[j]);
    }
  }
  __syncthreads();

  // Gram MFMA: wave -> 16x16 quadrant, K=128 (whole tile)
  const int wave = t >> 6;
  const int lane = t & 63;
  const int quad = lane >> 4;
  const int l15 = lane & 15;
  const int d0 = (wave & 1) * 16;
  const int e0 = (wave >> 1) * 16;
  f32x4_t acc = {0.f, 0.f, 0.f, 0.f};
#pragma unroll
  for (int kb = 0; kb < 4; ++kb) {
    const bf16x8_t avf = *reinterpret_cast<const bf16x8_t*>(
        &K3s[(d0 + l15) * 132 + kb * 32 + quad * 8]);
    const bf16x8_t bvf = *reinterpret_cast<const bf16x8_t*>(
        &Q3s[(e0 + l15) * 132 + kb * 32 + quad * 8]);
    acc = __builtin_amdgcn_mfma_f32_16x16x32_bf16(avf, bvf, acc, 0, 0, 0);
  }
  float* Gp = G + (size_t)((b * 8 + h) * 32) * 32;
#pragma unroll
  for (int r = 0; r < 4; ++r)
    atomicAdd(&Gp[(d0 + quad * 4 + r) * 32 + e0 + l15], acc[r]);

  if (t < 32) atomicAdd(&sqq[b * 256 + h * 32 + t], rbuf[t]);
  else if (t < 64) atomicAdd(&sqk[b * 256 + h * 32 + (t - 32)], rbuf[t]);
  else if (t < 96) atomicAdd(&vsum[b * 256 + h * 32 + (t - 64)], rbuf[t]);
}

// ---------------------------------------------------------------------------
// Border block-index remap: 92 positions.
__device__ __forceinline__ void border_map(int bi, int& bx, int& by) {
  if (bi < 16) { bx = bi; by = 0; }
  else if (bi < 32) { bx = bi - 16; by = 31; }
  else { const int e = bi - 32; by = 1 + (e >> 1); bx = (e & 1) * 15; }
}

// ---------------------------------------------------------------------------
// chain3: exact 3-stage path, BORDER grid (92,1,16). RED: 1=sumsq, 2=sum.
template <int RED, int BORDER>
__global__ __launch_bounds__(256) void chain3_kernel(
    const u16* __restrict__ in, u16* __restrict__ out,
    const float* __restrict__ w1g, const float* __restrict__ w2g,
    const float* __restrict__ w3g, float* __restrict__ red) {
  const int t = threadIdx.x;
  const int o = t & 3;
  const int bz = blockIdx.z;
  const int h = bz & 7;
  const int b = bz >> 3;
  int bx = blockIdx.x, by = blockIdx.y;
  if (BORDER) border_map(blockIdx.x, bx, by);
  const int x0 = bx * 16;
  const int y0 = by * 8;

  __shared__ __align__(16) u16 Abuf[308 * 32];
  __shared__ __align__(16) u16 Bbuf[240 * 32];
  __shared__ float rbuf[32];
  if (t < 32) rbuf[t] = 0.f;

  float w1[9], w2[9], w3[9];
#pragma unroll
  for (int k = 0; k < 9; ++k) {
    w1[k] = w1g[h * 9 + k];
    w2[k] = w2g[h * 9 + k];
    w3[k] = w3g[h * 9 + k];
  }

  for (int i = t; i < 308 * 4; i += 256) {
    const int px = i >> 2, oo = i & 3;
    const int lx = px % 22, ly = px / 22;
    const int gx = x0 - 3 + lx, gy = y0 - 3 + ly;
    uint4 v = {0, 0, 0, 0};
    if (gx >= 0 && gx < 256 && gy >= 0 && gy < 256)
      v = *reinterpret_cast<const uint4*>(
          in + ((size_t)((b << 16) + (gy << 8) + gx)) * 256 + h * 32 + oo * 8);
    *reinterpret_cast<uint4*>(Abuf + px * 32 + oo * 8) = v;
  }
  __syncthreads();

  for (int i = t; i < 240 * 4; i += 256) {
    const int px = i >> 2;
    const int sx = px % 20, sy = px / 20;
    const int gx = x0 - 2 + sx, gy = y0 - 2 + sy;
    const bool inb = (gx >= 0 && gx < 256 && gy >= 0 && gy < 256);
    float a[8] = {0, 0, 0, 0, 0, 0, 0, 0};
#pragma unroll
    for (int ky = 0; ky < 3; ++ky)
#pragma unroll
      for (int kx = 0; kx < 3; ++kx) {
        float f[8];
        unpack8(*reinterpret_cast<const uint4*>(
                    Abuf + ((sy + ky) * 22 + sx + kx) * 32 + o * 8), f);
#pragma unroll
        for (int j = 0; j < 8; ++j) a[j] = fmaf(w1[ky * 3 + kx], f[j], a[j]);
      }
    u16 ov[8];
#pragma unroll
    for (int j = 0; j < 8; ++j) ov[j] = inb ? f2bf(a[j]) : (u16)0;
    *reinterpret_cast<uint4*>(Bbuf + px * 32 + o * 8) = pack8(ov);
  }
  __syncthreads();

  for (int i = t; i < 180 * 4; i += 256) {
    const int px = i >> 2;
    const int sx = px % 18, sy = px / 18;
    const int gx = x0 - 1 + sx, gy = y0 - 1 + sy;
    const bool inb = (gx >= 0 && gx < 256 && gy >= 0 && gy < 256);
    float a[8] = {0, 0, 0, 0, 0, 0, 0, 0};
#pragma unroll
    for (int ky = 0; ky < 3; ++ky)
#pragma unroll
      for (int kx = 0; kx < 3; ++kx) {
        float f[8];
        unpack8(*reinterpret_cast<const uint4*>(
                    Bbuf + ((sy + ky) * 20 + sx + kx) * 32 + o * 8), f);
#pragma unroll
        for (int j = 0; j < 8; ++j) a[j] = fmaf(w2[ky * 3 + kx], f[j], a[j]);
      }
    u16 ov[8];
#pragma unroll
    for (int j = 0; j < 8; ++j) ov[j] = inb ? f2bf(a[j]) : (u16)0;
    *reinterpret_cast<uint4*>(Abuf + px * 32 + o * 8) = pack8(ov);
  }
  __syncthreads();

  float racc[8] = {0, 0, 0, 0, 0, 0, 0, 0};
  for (int i = t; i < 128 * 4; i += 256) {
    const int px = i >> 2;
    const int sx = px & 15, sy = px >> 4;
    float a[8] = {0, 0, 0, 0, 0, 0, 0, 0};
#pragma unroll
    for (int ky = 0; ky < 3; ++ky)
#pragma unroll
      for (int kx = 0; kx < 3; ++kx) {
        float f[8];
        unpack8(*reinterpret_cast<const uint4*>(
                    Abuf + ((sy + ky) * 18 + sx + kx) * 32 + o * 8), f);
#pragma unroll
        for (int j = 0; j < 8; ++j) a[j] = fmaf(w3[ky * 3 + kx], f[j], a[j]);
      }
    u16 ov[8];
#pragma unroll
    for (int j = 0; j < 8; ++j) {
      ov[j] = f2bf(a[j]);
      const float rv = bf2f(ov[j]);
      if (RED == 1) racc[j] = fmaf(rv, rv, racc[j]);
      if (RED == 2) racc[j] += rv;
    }
    u16* dst = out + ((size_t)((b << 16) + ((y0 + sy) << 8) + x0 + sx)) * 256 + h * 32 + o * 8;
    *reinterpret_cast<uint4*>(dst) = pack8(ov);
  }
  __syncthreads();
#pragma unroll
  for (int j = 0; j < 8; ++j) atomicAdd(&rbuf[o * 8 + j], racc[j]);
  __syncthreads();
  if (t < 32) atomicAdd(&red[b * 256 + h * 32 + t], rbuf[t]);
}

// ---------------------------------------------------------------------------
// kchain_gram: exact k chain fused with Gram vs q3 tile; BORDER grid only.
template <int BORDER>
__global__ __launch_bounds__(256) void kchain_gram_kernel(
    const u16* __restrict__ in, const u16* __restrict__ q3,
    const float* __restrict__ w1g, const float* __restrict__ w2g,
    const float* __restrict__ w3g, float* __restrict__ G, float* __restrict__ sqk) {
  const int t = threadIdx.x;
  const int o = t & 3;
  const int bz = blockIdx.z;
  const int h = bz & 7;
  const int b = bz >> 3;
  int bx = blockIdx.x, by = blockIdx.y;
  if (BORDER) border_map(blockIdx.x, bx, by);
  const int x0 = bx * 16;
  const int y0 = by * 8;

  __shared__ __align__(16) u16 Abuf[308 * 32];
  __shared__ __align__(16) u16 Bbuf[240 * 32];
  __shared__ __align__(16) u16 K3s[32 * 132];
  __shared__ __align__(16) u16 Q3s[32 * 132];
  __shared__ float rbuf[32];
  if (t < 32) rbuf[t] = 0.f;

  float w1[9], w2[9], w3[9];
#pragma unroll
  for (int k = 0; k < 9; ++k) {
    w1[k] = w1g[h * 9 + k];
    w2[k] = w2g[h * 9 + k];
    w3[k] = w3g[h * 9 + k];
  }

  for (int i = t; i < 308 * 4; i += 256) {
    const int px = i >> 2, oo = i & 3;
    const int lx = px % 22, ly = px / 22;
    const int gx = x0 - 3 + lx, gy = y0 - 3 + ly;
    uint4 v = {0, 0, 0, 0};
    if (gx >= 0 && gx < 256 && gy >= 0 && gy < 256)
      v = *reinterpret_cast<const uint4*>(
          in + ((size_t)((b << 16) + (gy << 8) + gx)) * 256 + h * 32 + oo * 8);
    *reinterpret_cast<uint4*>(Abuf + px * 32 + oo * 8) = v;
  }
  __syncthreads();

  for (int i = t; i < 240 * 4; i += 256) {
    const int px = i >> 2;
    const int sx = px % 20, sy = px / 20;
    const int gx = x0 - 2 + sx, gy = y0 - 2 + sy;
    const bool inb = (gx >= 0 && gx < 256 && gy >= 0 && gy < 256);
    float a[8] = {0, 0, 0, 0, 0, 0, 0, 0};
#pragma unroll
    for (int ky = 0; ky < 3; ++ky)
#pragma unroll
      for (int kx = 0; kx < 3; ++kx) {
        float f[8];
        unpack8(*reinterpret_cast<const uint4*>(
                    Abuf + ((sy + ky) * 22 + sx + kx) * 32 + o * 8), f);
#pragma unroll
        for (int j = 0; j < 8; ++j) a[j] = fmaf(w1[ky * 3 + kx], f[j], a[j]);
      }
    u16 ov[8];
#pragma unroll
    for (int j = 0; j < 8; ++j) ov[j] = inb ? f2bf(a[j]) : (u16)0;
    *reinterpret_cast<uint4*>(Bbuf + px * 32 + o * 8) = pack8(ov);
  }
  __syncthreads();

  for (int i = t; i < 180 * 4; i += 256) {
    const int px = i >> 2;
    const int sx = px % 18, sy = px / 18;
    const int gx = x0 - 1 + sx, gy = y0 - 1 + sy;
    const bool inb = (gx >= 0 && gx < 256 && gy >= 0 && gy < 256);
    float a[8] = {0, 0, 0, 0, 0, 0, 0, 0};
#pragma unroll
    for (int ky = 0; ky < 3; ++ky)
#pragma unroll
      for (int kx = 0; kx < 3; ++kx) {
        float f[8];
        unpack8(*reinterpret_cast<const uint4*>(
                    Bbuf + ((sy + ky) * 20 + sx + kx) * 32 + o * 8), f);
#pragma unroll
        for (int j = 0; j < 8; ++j) a[j] = fmaf(w2[ky * 3 + kx], f[j], a[j]);
      }
    u16 ov[8];
#pragma unroll
    for (int j = 0; j < 8; ++j) ov[j] = inb ? f2bf(a[j]) : (u16)0;
    *reinterpret_cast<uint4*>(Abuf + px * 32 + o * 8) = pack8(ov);
  }
  __syncthreads();

  float racc[8] = {0, 0, 0, 0, 0, 0, 0, 0};
  for (int i = t; i < 128 * 4; i += 256) {
    const int px = i >> 2;
    const int sx = px & 15, sy = px >> 4;
    float a[8] = {0, 0, 0, 0, 0, 0, 0, 0};
#pragma unroll
    for (int ky = 0; ky < 3; ++ky)
#pragma unroll
      for (int kx = 0; kx < 3; ++kx) {
        float f[8];
        unpack8(*reinterpret_cast<const uint4*>(
                    Abuf + ((sy + ky) * 18 + sx + kx) * 32 + o * 8), f);
#pragma unroll
        for (int j = 0; j < 8; ++j) a[j] = fmaf(w3[ky * 3 + kx], f[j], a[j]);
      }
#pragma unroll
    for (int j = 0; j < 8; ++j) {
      const u16 kb16 = f2bf(a[j]);
      const float kv = bf2f(kb16);
      K3s[(o * 8 + j) * 132 + px] = kb16;
      racc[j] = fmaf(kv, kv, racc[j]);
    }
    const uint4 uq = *reinterpret_cast<const uint4*>(
        q3 + ((size_t)((b << 16) + ((y0 + sy) << 8) + x0 + sx)) * 256 + h * 32 + o * 8);
    Q3s[(o * 8 + 0) * 132 + px] = (u16)(uq.x & 0xffffu);
    Q3s[(o * 8 + 1) * 132 + px] = (u16)(uq.x >> 16);
    Q3s[(o * 8 + 2) * 132 + px] = (u16)(uq.y & 0xffffu);
    Q3s[(o * 8 + 3) * 132 + px] = (u16)(uq.y >> 16);
    Q3s[(o * 8 + 4) * 132 + px] = (u16)(uq.z & 0xffffu);
    Q3s[(o * 8 + 5) * 132 + px] = (u16)(uq.z >> 16);
    Q3s[(o * 8 + 6) * 132 + px] = (u16)(uq.w & 0xffffu);
    Q3s[(o * 8 + 7) * 132 + px] = (u16)(uq.w >> 16);
  }
  __syncthreads();
#pragma unroll
  for (int j = 0; j < 8; ++j) atomicAdd(&rbuf[o * 8 + j], racc[j]);
  __syncthreads();
  if (t < 32) atomicAdd(&sqk[b * 256 + h * 32 + t], rbuf[t]);

  const int wave = t >> 6;
  const int lane = t & 63;
  const int quad = lane >> 4;
  const int l15 = lane & 15;
  const int d0 = (wave & 1) * 16;
  const int e0 = (wave >> 1) * 16;
  f32x4_t acc = {0.f, 0.f, 0.f, 0.f};
#pragma unroll
  for (int kb = 0; kb < 4; ++kb) {
    const bf16x8_t av = *reinterpret_cast<const bf16x8_t*>(
        &K3s[(d0 + l15) * 132 + kb * 32 + quad * 8]);
    const bf16x8_t bv = *reinterpret_cast<const bf16x8_t*>(
        &Q3s[(e0 + l15) * 132 + kb * 32 + quad * 8]);
    acc = __builtin_amdgcn_mfma_f32_16x16x32_bf16(av, bv, acc, 0, 0, 0);
  }
  float* Gp = G + (size_t)((b * 8 + h) * 32) * 32;
#pragma unroll
  for (int r = 0; r < 4; ++r)
    atomicAdd(&Gp[(d0 + quad * 4 + r) * 32 + e0 + l15], acc[r]);
}

// ---------------------------------------------------------------------------
// attn finalize: normalize Gram, conv1d diag, softmax.
__global__ __launch_bounds__(256) void attn_kernel(
    const float* __restrict__ G, const float* __restrict__ sqq,
    const float* __restrict__ sqk, const float* __restrict__ vsum,
    const float* __restrict__ cw, const float* __restrict__ cb,
    const float* __restrict__ rs1, const float* __restrict__ rs2,
    float* __restrict__ attn) {
  const int b = blockIdx.x;
  const int t = threadIdx.x;
  const int h = t >> 5;
  const int d = t & 31;
  __shared__ float vm[8][34];
  __shared__ float nq[256];
  vm[h][d + 1] = vsum[b * 256 + t] * (1.0f / 65536.0f);
  if (t < 8) { vm[t][0] = 0.f; vm[t][33] = 0.f; }
  nq[t] = fmaxf(sqrtf(sqq[b * 256 + t]), 1e-12f);
  __syncthreads();

  float av = cb[h];
#pragma unroll
  for (int i = 0; i < 8; ++i)
#pragma unroll
    for (int tau = 0; tau < 3; ++tau)
      av = fmaf(cw[h * 24 + i * 3 + tau], vm[i][d + tau], av);

  const float nk = fmaxf(sqrtf(sqk[b * 256 + t]), 1e-12f);
  const float rsc = rs1[h];
  const float rsc2 = rs2[h];
  const float* Gp = G + (size_t)((b * 8 + h) * 32 + d) * 32;
  float L[32];
#pragma unroll
  for (int e = 0; e < 32; ++e) {
    float l = Gp[e] * rsc / (nk * nq[h * 32 + e]);
    if (e == d) l += av * rsc2;
    L[e] = l;
  }
  float mx = L[0];
#pragma unroll
  for (int e = 1; e < 32; ++e) mx = fmaxf(mx, L[e]);
  float s = 0.f;
#pragma unroll
  for (int e = 0; e < 32; ++e) {
    L[e] = expf(L[e] - mx);
    s += L[e];
  }
  const float inv = 1.0f / s;
  float* Ap = attn + (size_t)((b * 8 + h) * 32 + d) * 32;
#pragma unroll
  for (int e = 0; e < 32; ++e) Ap[e] = L[e] * inv;
}

// M_b[c'][h*32+e] = sum_d proj_w[c'][h*32+d] * attn[b,h,d,e]  (bf16)
__global__ __launch_bounds__(256) void mbuild_kernel(
    const float* __restrict__ attn, const float* __restrict__ pw,
    u16* __restrict__ M) {
  const int bid = blockIdx.x;
  const int b = bid >> 3;
  const int h = bid & 7;
  const int t = threadIdx.x;
  __shared__ float at[32][33];
#pragma unroll
  for (int i = 0; i < 4; ++i) {
    const int idx = t * 4 + i;
    at[idx >> 5][idx & 31] = attn[(size_t)(b * 8 + h) * 1024 + idx];
  }
  __syncthreads();
  float pwf[32];
#pragma unroll
  for (int dd = 0; dd < 32; ++dd) pwf[dd] = pw[(size_t)t * 256 + h * 32 + dd];
  u16* Mp = M + (size_t)b * 65536 + (size_t)t * 256 + h * 32;
#pragma unroll
  for (int e = 0; e < 32; ++e) {
    float s = 0.f;
#pragma unroll
    for (int dd = 0; dd < 32; ++dd) s = fmaf(pwf[dd], at[dd][e], s);
    Mp[e] = f2bf(s);
  }
}

// out[m][c'] = sum_k v3[m][k] * M_b[c'][k] + proj_b[c'].  128x64 tile, fp32 out.
__global__ __launch_bounds__(256) void gemm_kernel(
    const u16* __restrict__ V, const u16* __restrict__ Mm,
    const float* __restrict__ pb, float* __restrict__ out) {
  const int m0 = blockIdx.x * 128;
  const int n0 = blockIdx.y * 64;
  const int b = m0 >> 16;
  const u16* Mb = Mm + (size_t)b * 65536;

  __shared__ __align__(16) u16 As[128][72];
  __shared__ __align__(16) u16 Bs[64][72];

  const int t = threadIdx.x;
  const int wave = t >> 6;
  const int lane = t & 63;
  const int quad = lane >> 4;
  const int l15 = lane & 15;

  f32x4_t acc[2][4];
#pragma unroll
  for (int mt = 0; mt < 2; ++mt)
#pragma unroll
    for (int nt = 0; nt < 4; ++nt) acc[mt][nt] = {0.f, 0.f, 0.f, 0.f};

  for (int k0 = 0; k0 < 256; k0 += 64) {
#pragma unroll
    for (int i = 0; i < 4; ++i) {
      const int id = t + 256 * i;
      const int row = id >> 3;
      const int c8 = id & 7;
      *reinterpret_cast<uint4*>(&As[row][c8 * 8]) = *reinterpret_cast<const uint4*>(
          &V[(size_t)(m0 + row) * 256 + k0 + c8 * 8]);
    }
#pragma unroll
    for (int i = 0; i < 2; ++i) {
      const int id = t + 256 * i;
      const int row = id >> 3;
      const int c8 = id & 7;
      *reinterpret_cast<uint4*>(&Bs[row][c8 * 8]) = *reinterpret_cast<const uint4*>(
          &Mb[(size_t)(n0 + row) * 256 + k0 + c8 * 8]);
    }
    __syncthreads();
#pragma unroll
    for (int ks = 0; ks < 2; ++ks) {
      bf16x8_t af[2], bfv[4];
#pragma unroll
      for (int mt = 0; mt < 2; ++mt)
        af[mt] = *reinterpret_cast<const bf16x8_t*>(
            &As[wave * 32 + mt * 16 + l15][ks * 32 + quad * 8]);
#pragma unroll
      for (int nt = 0; nt < 4; ++nt)
        bfv[nt] = *reinterpret_cast<const bf16x8_t*>(
            &Bs[nt * 16 + l15][ks * 32 + quad * 8]);
#pragma unroll
      for (int mt = 0; mt < 2; ++mt)
#pragma unroll
        for (int nt = 0; nt < 4; ++nt)
          acc[mt][nt] =
              __builtin_amdgcn_mfma_f32_16x16x32_bf16(af[mt], bfv[nt], acc[mt][nt], 0, 0, 0);
    }
    __syncthreads();
  }

#pragma unroll
  for (int nt = 0; nt < 4; ++nt) {
    const int col = n0 + nt * 16 + l15;
    const float pbf = pb[col];
#pragma unroll
    for (int mt = 0; mt < 2; ++mt) {
#pragma unroll
      for (int r = 0; r < 4; ++r) {
        const int m = m0 + wave * 32 + mt * 16 + quad * 4 + r;
        out[(size_t)m * 256 + col] = acc[mt][nt][r] + pbf;
      }
    }
  }
}

extern "C" void kernel_launch(void* const* d_in, const int* in_sizes, int n_in,
                              void* d_out, int out_size, void* d_ws, size_t ws_size,
                              hipStream_t stream) {
  const float* x_in = (const float*)d_in[0];
  const float* qw1 = (const float*)d_in[1];
  const float* qw2 = (const float*)d_in[2];
  const float* qw3 = (const float*)d_in[3];
  const float* kw1 = (const float*)d_in[4];
  const float* kw2 = (const float*)d_in[5];
  const float* kw3 = (const float*)d_in[6];
  const float* vw1 = (const float*)d_in[7];
  const float* vw2 = (const float*)d_in[8];
  const float* vw3 = (const float*)d_in[9];
  const float* posw1 = (const float*)d_in[10];
  const float* posb1 = (const float*)d_in[11];
  const float* posw2 = (const float*)d_in[12];
  const float* posb2 = (const float*)d_in[13];
  const float* cw = (const float*)d_in[14];
  const float* cb = (const float*)d_in[15];
  const float* rs1 = (const float*)d_in[16];
  const float* rs2 = (const float*)d_in[17];
  const float* pw = (const float*)d_in[18];
  const float* pb = (const float*)d_in[19];

  char* ws = (char*)d_ws;
  const size_t SLOT = 67108864;  // one (2,256,256,256) bf16 image
  u16* S0 = (u16*)(ws);            // x2
  u16* S1 = (u16*)(ws + SLOT);     // v3
  u16* D0 = (u16*)d_out;           // q3 (border tiles only; dead before gemm)
  char* SM = ws + 2 * SLOT;
  float* G = (float*)(SM);              // 2*8*32*32 f32
  float* sqq = (float*)(SM + 65536);
  float* sqk = (float*)(SM + 67584);
  float* vsum = (float*)(SM + 69632);
  float* attn = (float*)(SM + 71680);
  u16* Mm = (u16*)(SM + 137216);
  float* Wc = (float*)(SM + 399360);    // composed weights [8][3][49] f32 (4.7KB)

  hipMemsetAsync(SM, 0, 71680, stream);

  compose_kernel<<<1, 64, 0, stream>>>(qw1, qw2, qw3, kw1, kw2, kw3,
                                       vw1, vw2, vw3, Wc);

  const dim3 tgrid(16, 32, 16);
  posemb_kernel<<<tgrid, 256, 0, stream>>>(x_in, S0, posw1, posb1, posw2, posb2);

  // Interior: fused q/k/v composed-7x7 + Gram + reductions (bx 1..14, by 1..30)
  qkv_fused_kernel<<<dim3(14, 30, 16), 256, 0, stream>>>(S0, S1, Wc, G, sqq, sqk, vsum);

  // Border: exact 3-stage path on 92 remapped tile positions
  const dim3 bgrid(92, 1, 16);
  chain3_kernel<1, 1><<<bgrid, 256, 0, stream>>>(S0, D0, qw1, qw2, qw3, sqq);
  kchain_gram_kernel<1><<<bgrid, 256, 0, stream>>>(S0, D0, kw1, kw2, kw3, G, sqk);
  chain3_kernel<2, 1><<<bgrid, 256, 0, stream>>>(S0, S1, vw1, vw2, vw3, vsum);

  attn_kernel<<<2, 256, 0, stream>>>(G, sqq, sqk, vsum, cw, cb, rs1, rs2, attn);
  mbuild_kernel<<<16, 256, 0, stream>>>(attn, pw, Mm);
  gemm_kernel<<<dim3(1024, 4), 256, 0, stream>>>(S1, Mm, pb, (float*)d_out);
}

// Round 7
// 903.211 us; speedup vs baseline: 2.0570x; 2.0570x over previous
//
#include <hip/hip_runtime.h>
#include <stdint.h>
#include <math.h>

// MS_MSA fused pipeline:
//   compose_kernel : Weff[h][chain] = w1*w2*w3 composed 7x7 stencil (fp32, ws)
//   posemb_kernel  : x2 = x + dw2(gelu(dw1(x)+b1))+b2   (2-stage tile fusion)
//   qkv_fused      : INTERIOR tiles (r1-verified structure, 358us): single
//                    composed-7x7 joint sweep for q,k,v, iy loop ROLLED (keeps
//                    VGPR~64; unrolling explodes b128 hoisting -> spill, r5/r6).
//                    ONE change vs r1: weights staged to LDS, in-loop weight
//                    reads are ds_read (in-order, counted lgkmcnt) instead of
//                    wave-uniform global s_load (out-of-order SMEM forces
//                    lgkmcnt(0), draining the ds_read_b128 queue every iter).
//   chain3/kchain  : BORDER tiles only (92/512 positions) via exact 3-stage path.
//   attn/mbuild    : softmax + fold proj_w*blockdiag(attn) -> M
//   gemm           : out = v3 @ M_b^T + proj_b  (bf16 MFMA, fp32 out)
// ws: S0=x2, S1=v3 (2 x 64MiB) + smalls + Wc(4.7KB) — layout == verified r1.
// d_out scratch: [0,64MiB) q3 (border tiles only; dead before gemm).

using u16 = unsigned short;
using u32 = unsigned int;

typedef __bf16 bf16x8_t __attribute__((ext_vector_type(8)));
typedef float f32x4_t __attribute__((ext_vector_type(4)));

__device__ __forceinline__ float bf2f(u16 v) {
  u32 u = ((u32)v) << 16;
  return __builtin_bit_cast(float, u);
}
__device__ __forceinline__ u16 f2bf(float f) {
  u32 u = __builtin_bit_cast(u32, f);
  u32 r = u + 0x7fffu + ((u >> 16) & 1u);  // RNE (finite inputs)
  return (u16)(r >> 16);
}
__device__ __forceinline__ void unpack8(uint4 u, float f[8]) {
  f[0] = bf2f((u16)(u.x & 0xffffu)); f[1] = bf2f((u16)(u.x >> 16));
  f[2] = bf2f((u16)(u.y & 0xffffu)); f[3] = bf2f((u16)(u.y >> 16));
  f[4] = bf2f((u16)(u.z & 0xffffu)); f[5] = bf2f((u16)(u.z >> 16));
  f[6] = bf2f((u16)(u.w & 0xffffu)); f[7] = bf2f((u16)(u.w >> 16));
}
__device__ __forceinline__ uint4 pack8(const u16 o[8]) {
  uint4 v;
  v.x = (u32)o[0] | ((u32)o[1] << 16);
  v.y = (u32)o[2] | ((u32)o[3] << 16);
  v.z = (u32)o[4] | ((u32)o[5] << 16);
  v.w = (u32)o[6] | ((u32)o[7] << 16);
  return v;
}

// ---------------------------------------------------------------------------
// compose: Weff = w1 (*) w2 (*) w3 (kernel-array convolution; correlation
// offsets add). Wc[h][c][dy*7+dx], c: 0=q,1=k,2=v. 24 active threads.
__global__ __launch_bounds__(64) void compose_kernel(
    const float* __restrict__ qw1, const float* __restrict__ qw2,
    const float* __restrict__ qw3, const float* __restrict__ kw1,
    const float* __restrict__ kw2, const float* __restrict__ kw3,
    const float* __restrict__ vw1, const float* __restrict__ vw2,
    const float* __restrict__ vw3, float* __restrict__ Wc) {
  const int t = threadIdx.x;
  if (t >= 24) return;
  const int h = t / 3, c = t % 3;
  const float* w1 = (c == 0 ? qw1 : c == 1 ? kw1 : vw1) + h * 9;
  const float* w2 = (c == 0 ? qw2 : c == 1 ? kw2 : vw2) + h * 9;
  const float* w3 = (c == 0 ? qw3 : c == 1 ? kw3 : vw3) + h * 9;
  float w12[25];
  for (int i = 0; i < 25; ++i) w12[i] = 0.f;
  for (int ky = 0; ky < 3; ++ky)
    for (int kx = 0; kx < 3; ++kx)
      for (int ly = 0; ly < 3; ++ly)
        for (int lx = 0; lx < 3; ++lx)
          w12[(ky + ly) * 5 + kx + lx] += w2[ky * 3 + kx] * w1[ly * 3 + lx];
  float we[49];
  for (int i = 0; i < 49; ++i) we[i] = 0.f;
  for (int my = 0; my < 3; ++my)
    for (int mx = 0; mx < 3; ++mx)
      for (int ey = 0; ey < 5; ++ey)
        for (int ex = 0; ex < 5; ++ex)
          we[(my + ey) * 7 + mx + ex] += w3[my * 3 + mx] * w12[ey * 5 + ex];
  float* dst = Wc + (h * 3 + c) * 49;
  for (int i = 0; i < 49; ++i) dst[i] = we[i];
}

// ---------------------------------------------------------------------------
// posemb: 2-stage fused, per-channel weights, fp32 input, gelu, residual.
__global__ __launch_bounds__(256) void posemb_kernel(
    const float* __restrict__ xin, u16* __restrict__ x2,
    const float* __restrict__ w1g, const float* __restrict__ b1g,
    const float* __restrict__ w2g, const float* __restrict__ b2g) {
  const int t = threadIdx.x;
  const int o = t & 3;
  const int bz = blockIdx.z;
  const int cg = bz & 7;
  const int b = bz >> 3;
  const int x0 = blockIdx.x * 16;
  const int y0 = blockIdx.y * 8;
  const int c0 = cg * 32 + o * 8;

  __shared__ __align__(16) u16 Abuf[240 * 32];
  __shared__ __align__(16) u16 Bbuf[180 * 32];

  for (int i = t; i < 240 * 4; i += 256) {
    const int px = i >> 2, oo = i & 3;
    const int lx = px % 20, ly = px / 20;
    const int gx = x0 - 2 + lx, gy = y0 - 2 + ly;
    u16 ov[8];
    if (gx >= 0 && gx < 256 && gy >= 0 && gy < 256) {
      const float* p = xin + ((size_t)((b << 16) + (gy << 8) + gx)) * 256 + cg * 32 + oo * 8;
      const float4 r0 = *reinterpret_cast<const float4*>(p);
      const float4 r1 = *reinterpret_cast<const float4*>(p + 4);
      ov[0] = f2bf(r0.x); ov[1] = f2bf(r0.y); ov[2] = f2bf(r0.z); ov[3] = f2bf(r0.w);
      ov[4] = f2bf(r1.x); ov[5] = f2bf(r1.y); ov[6] = f2bf(r1.z); ov[7] = f2bf(r1.w);
    } else {
#pragma unroll
      for (int j = 0; j < 8; ++j) ov[j] = 0;
    }
    *reinterpret_cast<uint4*>(Abuf + px * 32 + oo * 8) = pack8(ov);
  }
  __syncthreads();

  {
    float w[72], bi[8];
#pragma unroll
    for (int j = 0; j < 8; ++j) {
#pragma unroll
      for (int k = 0; k < 9; ++k) w[j * 9 + k] = w1g[(c0 + j) * 9 + k];
      bi[j] = b1g[c0 + j];
    }
    for (int i = t; i < 180 * 4; i += 256) {
      const int px = i >> 2;
      const int sx = px % 18, sy = px / 18;
      const int gx = x0 - 1 + sx, gy = y0 - 1 + sy;
      const bool inb = (gx >= 0 && gx < 256 && gy >= 0 && gy < 256);
      float a[8];
#pragma unroll
      for (int j = 0; j < 8; ++j) a[j] = bi[j];
#pragma unroll
      for (int ky = 0; ky < 3; ++ky)
#pragma unroll
        for (int kx = 0; kx < 3; ++kx) {
          float f[8];
          unpack8(*reinterpret_cast<const uint4*>(
                      Abuf + ((sy + ky) * 20 + sx + kx) * 32 + o * 8), f);
#pragma unroll
          for (int j = 0; j < 8; ++j) a[j] = fmaf(w[j * 9 + ky * 3 + kx], f[j], a[j]);
        }
      u16 ov[8];
#pragma unroll
      for (int j = 0; j < 8; ++j) {
        const float g = 0.5f * a[j] * (1.0f + erff(a[j] * 0.70710678118654752f));
        ov[j] = inb ? f2bf(g) : (u16)0;
      }
      *reinterpret_cast<uint4*>(Bbuf + px * 32 + o * 8) = pack8(ov);
    }
  }
  __syncthreads();

  {
    float w[72], bi[8];
#pragma unroll
    for (int j = 0; j < 8; ++j) {
#pragma unroll
      for (int k = 0; k < 9; ++k) w[j * 9 + k] = w2g[(c0 + j) * 9 + k];
      bi[j] = b2g[c0 + j];
    }
    for (int i = t; i < 128 * 4; i += 256) {
      const int px = i >> 2;
      const int sx = px & 15, sy = px >> 4;
      float a[8];
#pragma unroll
      for (int j = 0; j < 8; ++j) a[j] = bi[j];
#pragma unroll
      for (int ky = 0; ky < 3; ++ky)
#pragma unroll
        for (int kx = 0; kx < 3; ++kx) {
          float f[8];
          unpack8(*reinterpret_cast<const uint4*>(
                      Bbuf + ((sy + ky) * 18 + sx + kx) * 32 + o * 8), f);
#pragma unroll
          for (int j = 0; j < 8; ++j) a[j] = fmaf(w[j * 9 + ky * 3 + kx], f[j], a[j]);
        }
      float xr[8];
      unpack8(*reinterpret_cast<const uint4*>(
                  Abuf + ((sy + 2) * 20 + sx + 2) * 32 + o * 8), xr);
      u16 ov[8];
#pragma unroll
      for (int j = 0; j < 8; ++j) ov[j] = f2bf(a[j] + xr[j]);
      u16* dst = x2 + ((size_t)((b << 16) + ((y0 + sy) << 8) + x0 + sx)) * 256 + cg * 32 + o * 8;
      *reinterpret_cast<uint4*>(dst) = pack8(ov);
    }
  }
}

// ---------------------------------------------------------------------------
// qkv_fused: interior tiles only (bx 1..14, by 1..30 of the 16x8 tiling).
// One 22x14 halo load; joint composed-7x7 sweep for q,k,v (shared LDS data
// reads). Weights in LDS (in-order ds_read, counted lgkmcnt — NOT s_load).
// iy loop rolled (r1-verified; unrolling spills). Epilogue: Gram MFMA
// (staging aliases dead Abuf), reductions, v3 store. Thread: o=t&3 (8 ch),
// sx=(t>>2)&15, yg=t>>6 -> output rows yg*2, yg*2+1.
__global__ __launch_bounds__(256) void qkv_fused_kernel(
    const u16* __restrict__ x2, u16* __restrict__ v3out,
    const float* __restrict__ Wc, float* __restrict__ G,
    float* __restrict__ sqq, float* __restrict__ sqk,
    float* __restrict__ vsum) {
  const int t = threadIdx.x;
  const int o = t & 3;
  const int sx = (t >> 2) & 15;
  const int yg = t >> 6;
  const int bz = blockIdx.z;
  const int h = bz & 7;
  const int b = bz >> 3;
  const int x0 = (blockIdx.x + 1) * 16;
  const int y0 = (blockIdx.y + 1) * 8;

  __shared__ __align__(16) u16 Abuf[308 * 32];  // halo 22x14; later K3s/Q3s
  __shared__ float Wl[147];
  __shared__ float rbuf[96];
  if (t < 96) rbuf[t] = 0.f;
  if (t >= 96 && t < 96 + 147) Wl[t - 96] = Wc[h * 147 + (t - 96)];

  // P0: load halo (interior -> no bounds checks)
  for (int i = t; i < 308 * 4; i += 256) {
    const int px = i >> 2, oo = i & 3;
    const int lx = px % 22, ly = px / 22;
    const int gx = x0 - 3 + lx, gy = y0 - 3 + ly;
    *reinterpret_cast<uint4*>(Abuf + px * 32 + oo * 8) =
        *reinterpret_cast<const uint4*>(
            x2 + ((size_t)((b << 16) + (gy << 8) + gx)) * 256 + h * 32 + oo * 8);
  }
  __syncthreads();

  const float* Wq = Wl;        // LDS-resident weights
  const float* Wk = Wl + 49;
  const float* Wv = Wl + 98;

  float aq[2][8], ak[2][8], av2[2][8];
#pragma unroll
  for (int r = 0; r < 2; ++r)
#pragma unroll
    for (int j = 0; j < 8; ++j) { aq[r][j] = 0.f; ak[r][j] = 0.f; av2[r][j] = 0.f; }

  const int ty0 = yg * 2;
  const u16* Arow0 = Abuf + (ty0 * 22 + sx) * 32 + o * 8;

  // iy = 0: serves ry=0 only (dy=0)
  {
    const u16* Ar = Arow0;
#pragma unroll
    for (int jx = 0; jx < 7; ++jx) {
      float f[8];
      unpack8(*reinterpret_cast<const uint4*>(Ar + jx * 32), f);
      const float wq = Wq[jx], wk = Wk[jx], wv = Wv[jx];
#pragma unroll
      for (int j = 0; j < 8; ++j) {
        aq[0][j] = fmaf(wq, f[j], aq[0][j]);
        ak[0][j] = fmaf(wk, f[j], ak[0][j]);
        av2[0][j] = fmaf(wv, f[j], av2[0][j]);
      }
    }
  }
  // iy = 1..6: serves ry=0 (dy=iy) and ry=1 (dy=iy-1). Rolled (unroll -> spill).
#pragma unroll 1
  for (int iy = 1; iy <= 6; ++iy) {
    const u16* Ar = Arow0 + iy * (22 * 32);
    const float* wq0 = Wq + iy * 7;
    const float* wk0 = Wk + iy * 7;
    const float* wv0 = Wv + iy * 7;
#pragma unroll
    for (int jx = 0; jx < 7; ++jx) {
      float f[8];
      unpack8(*reinterpret_cast<const uint4*>(Ar + jx * 32), f);
      float w;
      w = wq0[jx];
#pragma unroll
      for (int j = 0; j < 8; ++j) aq[0][j] = fmaf(w, f[j], aq[0][j]);
      w = wq0[jx - 7];
#pragma unroll
      for (int j = 0; j < 8; ++j) aq[1][j] = fmaf(w, f[j], aq[1][j]);
      w = wk0[jx];
#pragma unroll
      for (int j = 0; j < 8; ++j) ak[0][j] = fmaf(w, f[j], ak[0][j]);
      w = wk0[jx - 7];
#pragma unroll
      for (int j = 0; j < 8; ++j) ak[1][j] = fmaf(w, f[j], ak[1][j]);
      w = wv0[jx];
#pragma unroll
      for (int j = 0; j < 8; ++j) av2[0][j] = fmaf(w, f[j], av2[0][j]);
      w = wv0[jx - 7];
#pragma unroll
      for (int j = 0; j < 8; ++j) av2[1][j] = fmaf(w, f[j], av2[1][j]);
    }
  }
  // iy = 7: serves ry=1 only (dy=6)
  {
    const u16* Ar = Arow0 + 7 * (22 * 32);
#pragma unroll
    for (int jx = 0; jx < 7; ++jx) {
      float f[8];
      unpack8(*reinterpret_cast<const uint4*>(Ar + jx * 32), f);
      const float wq = Wq[42 + jx], wk = Wk[42 + jx], wv = Wv[42 + jx];
#pragma unroll
      for (int j = 0; j < 8; ++j) {
        aq[1][j] = fmaf(wq, f[j], aq[1][j]);
        ak[1][j] = fmaf(wk, f[j], ak[1][j]);
        av2[1][j] = fmaf(wv, f[j], av2[1][j]);
      }
    }
  }

  __syncthreads();  // all Abuf reads done -> safe to alias staging into it

  u16* K3s = Abuf;             // [32][132]
  u16* Q3s = Abuf + 32 * 132;  // [32][132]

  float rq[8], rk[8], rv[8];
#pragma unroll
  for (int j = 0; j < 8; ++j) { rq[j] = 0.f; rk[j] = 0.f; rv[j] = 0.f; }
#pragma unroll
  for (int ry = 0; ry < 2; ++ry) {
    const int px = (ty0 + ry) * 16 + sx;
    u16 ov[8];
#pragma unroll
    for (int j = 0; j < 8; ++j) {
      const u16 qb = f2bf(aq[ry][j]);
      Q3s[(o * 8 + j) * 132 + px] = qb;
      const float qf = bf2f(qb);
      rq[j] = fmaf(qf, qf, rq[j]);
      const u16 kb = f2bf(ak[ry][j]);
      K3s[(o * 8 + j) * 132 + px] = kb;
      const float kf = bf2f(kb);
      rk[j] = fmaf(kf, kf, rk[j]);
      ov[j] = f2bf(av2[ry][j]);
      rv[j] += bf2f(ov[j]);
    }
    u16* dst = v3out + ((size_t)((b << 16) + ((y0 + ty0 + ry) << 8) + x0 + sx)) * 256 + h * 32 + o * 8;
    *reinterpret_cast<uint4*>(dst) = pack8(ov);
  }
#pragma unroll
  for (int j = 0; j < 8; ++j) {
    atomicAdd(&rbuf[o * 8 + j], rq[j]);
    atomicAdd(&rbuf[32 + o * 8 + j], rk[j]);
    atomicAdd(&rbuf[64 + o * 8 + j], rv[j]);
  }
  __syncthreads();

  // Gram MFMA: wave -> 16x16 quadrant, K=128 (whole tile)
  const int wave = t >> 6;
  const int lane = t & 63;
  const int quad = lane >> 4;
  const int l15 = lane & 15;
  const int d0 = (wave & 1) * 16;
  const int e0 = (wave >> 1) * 16;
  f32x4_t acc = {0.f, 0.f, 0.f, 0.f};
#pragma unroll
  for (int kb = 0; kb < 4; ++kb) {
    const bf16x8_t avf = *reinterpret_cast<const bf16x8_t*>(
        &K3s[(d0 + l15) * 132 + kb * 32 + quad * 8]);
    const bf16x8_t bvf = *reinterpret_cast<const bf16x8_t*>(
        &Q3s[(e0 + l15) * 132 + kb * 32 + quad * 8]);
    acc = __builtin_amdgcn_mfma_f32_16x16x32_bf16(avf, bvf, acc, 0, 0, 0);
  }
  float* Gp = G + (size_t)((b * 8 + h) * 32) * 32;
#pragma unroll
  for (int r = 0; r < 4; ++r)
    atomicAdd(&Gp[(d0 + quad * 4 + r) * 32 + e0 + l15], acc[r]);

  if (t < 32) atomicAdd(&sqq[b * 256 + h * 32 + t], rbuf[t]);
  else if (t < 64) atomicAdd(&sqk[b * 256 + h * 32 + (t - 32)], rbuf[t]);
  else if (t < 96) atomicAdd(&vsum[b * 256 + h * 32 + (t - 64)], rbuf[t]);
}

// ---------------------------------------------------------------------------
// Border block-index remap: 92 positions.
__device__ __forceinline__ void border_map(int bi, int& bx, int& by) {
  if (bi < 16) { bx = bi; by = 0; }
  else if (bi < 32) { bx = bi - 16; by = 31; }
  else { const int e = bi - 32; by = 1 + (e >> 1); bx = (e & 1) * 15; }
}

// ---------------------------------------------------------------------------
// chain3: exact 3-stage path, BORDER grid (92,1,16). RED: 1=sumsq, 2=sum.
template <int RED, int BORDER>
__global__ __launch_bounds__(256) void chain3_kernel(
    const u16* __restrict__ in, u16* __restrict__ out,
    const float* __restrict__ w1g, const float* __restrict__ w2g,
    const float* __restrict__ w3g, float* __restrict__ red) {
  const int t = threadIdx.x;
  const int o = t & 3;
  const int bz = blockIdx.z;
  const int h = bz & 7;
  const int b = bz >> 3;
  int bx = blockIdx.x, by = blockIdx.y;
  if (BORDER) border_map(blockIdx.x, bx, by);
  const int x0 = bx * 16;
  const int y0 = by * 8;

  __shared__ __align__(16) u16 Abuf[308 * 32];
  __shared__ __align__(16) u16 Bbuf[240 * 32];
  __shared__ float rbuf[32];
  if (t < 32) rbuf[t] = 0.f;

  float w1[9], w2[9], w3[9];
#pragma unroll
  for (int k = 0; k < 9; ++k) {
    w1[k] = w1g[h * 9 + k];
    w2[k] = w2g[h * 9 + k];
    w3[k] = w3g[h * 9 + k];
  }

  for (int i = t; i < 308 * 4; i += 256) {
    const int px = i >> 2, oo = i & 3;
    const int lx = px % 22, ly = px / 22;
    const int gx = x0 - 3 + lx, gy = y0 - 3 + ly;
    uint4 v = {0, 0, 0, 0};
    if (gx >= 0 && gx < 256 && gy >= 0 && gy < 256)
      v = *reinterpret_cast<const uint4*>(
          in + ((size_t)((b << 16) + (gy << 8) + gx)) * 256 + h * 32 + oo * 8);
    *reinterpret_cast<uint4*>(Abuf + px * 32 + oo * 8) = v;
  }
  __syncthreads();

  for (int i = t; i < 240 * 4; i += 256) {
    const int px = i >> 2;
    const int sx = px % 20, sy = px / 20;
    const int gx = x0 - 2 + sx, gy = y0 - 2 + sy;
    const bool inb = (gx >= 0 && gx < 256 && gy >= 0 && gy < 256);
    float a[8] = {0, 0, 0, 0, 0, 0, 0, 0};
#pragma unroll
    for (int ky = 0; ky < 3; ++ky)
#pragma unroll
      for (int kx = 0; kx < 3; ++kx) {
        float f[8];
        unpack8(*reinterpret_cast<const uint4*>(
                    Abuf + ((sy + ky) * 22 + sx + kx) * 32 + o * 8), f);
#pragma unroll
        for (int j = 0; j < 8; ++j) a[j] = fmaf(w1[ky * 3 + kx], f[j], a[j]);
      }
    u16 ov[8];
#pragma unroll
    for (int j = 0; j < 8; ++j) ov[j] = inb ? f2bf(a[j]) : (u16)0;
    *reinterpret_cast<uint4*>(Bbuf + px * 32 + o * 8) = pack8(ov);
  }
  __syncthreads();

  for (int i = t; i < 180 * 4; i += 256) {
    const int px = i >> 2;
    const int sx = px % 18, sy = px / 18;
    const int gx = x0 - 1 + sx, gy = y0 - 1 + sy;
    const bool inb = (gx >= 0 && gx < 256 && gy >= 0 && gy < 256);
    float a[8] = {0, 0, 0, 0, 0, 0, 0, 0};
#pragma unroll
    for (int ky = 0; ky < 3; ++ky)
#pragma unroll
      for (int kx = 0; kx < 3; ++kx) {
        float f[8];
        unpack8(*reinterpret_cast<const uint4*>(
                    Bbuf + ((sy + ky) * 20 + sx + kx) * 32 + o * 8), f);
#pragma unroll
        for (int j = 0; j < 8; ++j) a[j] = fmaf(w2[ky * 3 + kx], f[j], a[j]);
      }
    u16 ov[8];
#pragma unroll
    for (int j = 0; j < 8; ++j) ov[j] = inb ? f2bf(a[j]) : (u16)0;
    *reinterpret_cast<uint4*>(Abuf + px * 32 + o * 8) = pack8(ov);
  }
  __syncthreads();

  float racc[8] = {0, 0, 0, 0, 0, 0, 0, 0};
  for (int i = t; i < 128 * 4; i += 256) {
    const int px = i >> 2;
    const int sx = px & 15, sy = px >> 4;
    float a[8] = {0, 0, 0, 0, 0, 0, 0, 0};
#pragma unroll
    for (int ky = 0; ky < 3; ++ky)
#pragma unroll
      for (int kx = 0; kx < 3; ++kx) {
        float f[8];
        unpack8(*reinterpret_cast<const uint4*>(
                    Abuf + ((sy + ky) * 18 + sx + kx) * 32 + o * 8), f);
#pragma unroll
        for (int j = 0; j < 8; ++j) a[j] = fmaf(w3[ky * 3 + kx], f[j], a[j]);
      }
    u16 ov[8];
#pragma unroll
    for (int j = 0; j < 8; ++j) {
      ov[j] = f2bf(a[j]);
      const float rv = bf2f(ov[j]);
      if (RED == 1) racc[j] = fmaf(rv, rv, racc[j]);
      if (RED == 2) racc[j] += rv;
    }
    u16* dst = out + ((size_t)((b << 16) + ((y0 + sy) << 8) + x0 + sx)) * 256 + h * 32 + o * 8;
    *reinterpret_cast<uint4*>(dst) = pack8(ov);
  }
  __syncthreads();
#pragma unroll
  for (int j = 0; j < 8; ++j) atomicAdd(&rbuf[o * 8 + j], racc[j]);
  __syncthreads();
  if (t < 32) atomicAdd(&red[b * 256 + h * 32 + t], rbuf[t]);
}

// ---------------------------------------------------------------------------
// kchain_gram: exact k chain fused with Gram vs q3 tile; BORDER grid only.
template <int BORDER>
__global__ __launch_bounds__(256) void kchain_gram_kernel(
    const u16* __restrict__ in, const u16* __restrict__ q3,
    const float* __restrict__ w1g, const float* __restrict__ w2g,
    const float* __restrict__ w3g, float* __restrict__ G, float* __restrict__ sqk) {
  const int t = threadIdx.x;
  const int o = t & 3;
  const int bz = blockIdx.z;
  const int h = bz & 7;
  const int b = bz >> 3;
  int bx = blockIdx.x, by = blockIdx.y;
  if (BORDER) border_map(blockIdx.x, bx, by);
  const int x0 = bx * 16;
  const int y0 = by * 8;

  __shared__ __align__(16) u16 Abuf[308 * 32];
  __shared__ __align__(16) u16 Bbuf[240 * 32];
  __shared__ __align__(16) u16 K3s[32 * 132];
  __shared__ __align__(16) u16 Q3s[32 * 132];
  __shared__ float rbuf[32];
  if (t < 32) rbuf[t] = 0.f;

  float w1[9], w2[9], w3[9];
#pragma unroll
  for (int k = 0; k < 9; ++k) {
    w1[k] = w1g[h * 9 + k];
    w2[k] = w2g[h * 9 + k];
    w3[k] = w3g[h * 9 + k];
  }

  for (int i = t; i < 308 * 4; i += 256) {
    const int px = i >> 2, oo = i & 3;
    const int lx = px % 22, ly = px / 22;
    const int gx = x0 - 3 + lx, gy = y0 - 3 + ly;
    uint4 v = {0, 0, 0, 0};
    if (gx >= 0 && gx < 256 && gy >= 0 && gy < 256)
      v = *reinterpret_cast<const uint4*>(
          in + ((size_t)((b << 16) + (gy << 8) + gx)) * 256 + h * 32 + oo * 8);
    *reinterpret_cast<uint4*>(Abuf + px * 32 + oo * 8) = v;
  }
  __syncthreads();

  for (int i = t; i < 240 * 4; i += 256) {
    const int px = i >> 2;
    const int sx = px % 20, sy = px / 20;
    const int gx = x0 - 2 + sx, gy = y0 - 2 + sy;
    const bool inb = (gx >= 0 && gx < 256 && gy >= 0 && gy < 256);
    float a[8] = {0, 0, 0, 0, 0, 0, 0, 0};
#pragma unroll
    for (int ky = 0; ky < 3; ++ky)
#pragma unroll
      for (int kx = 0; kx < 3; ++kx) {
        float f[8];
        unpack8(*reinterpret_cast<const uint4*>(
                    Abuf + ((sy + ky) * 22 + sx + kx) * 32 + o * 8), f);
#pragma unroll
        for (int j = 0; j < 8; ++j) a[j] = fmaf(w1[ky * 3 + kx], f[j], a[j]);
      }
    u16 ov[8];
#pragma unroll
    for (int j = 0; j < 8; ++j) ov[j] = inb ? f2bf(a[j]) : (u16)0;
    *reinterpret_cast<uint4*>(Bbuf + px * 32 + o * 8) = pack8(ov);
  }
  __syncthreads();

  for (int i = t; i < 180 * 4; i += 256) {
    const int px = i >> 2;
    const int sx = px % 18, sy = px / 18;
    const int gx = x0 - 1 + sx, gy = y0 - 1 + sy;
    const bool inb = (gx >= 0 && gx < 256 && gy >= 0 && gy < 256);
    float a[8] = {0, 0, 0, 0, 0, 0, 0, 0};
#pragma unroll
    for (int ky = 0; ky < 3; ++ky)
#pragma unroll
      for (int kx = 0; kx < 3; ++kx) {
        float f[8];
        unpack8(*reinterpret_cast<const uint4*>(
                    Bbuf + ((sy + ky) * 20 + sx + kx) * 32 + o * 8), f);
#pragma unroll
        for (int j = 0; j < 8; ++j) a[j] = fmaf(w2[ky * 3 + kx], f[j], a[j]);
      }
    u16 ov[8];
#pragma unroll
    for (int j = 0; j < 8; ++j) ov[j] = inb ? f2bf(a[j]) : (u16)0;
    *reinterpret_cast<uint4*>(Abuf + px * 32 + o * 8) = pack8(ov);
  }
  __syncthreads();

  float racc[8] = {0, 0, 0, 0, 0, 0, 0, 0};
  for (int i = t; i < 128 * 4; i += 256) {
    const int px = i >> 2;
    const int sx = px & 15, sy = px >> 4;
    float a[8] = {0, 0, 0, 0, 0, 0, 0, 0};
#pragma unroll
    for (int ky = 0; ky < 3; ++ky)
#pragma unroll
      for (int kx = 0; kx < 3; ++kx) {
        float f[8];
        unpack8(*reinterpret_cast<const uint4*>(
                    Abuf + ((sy + ky) * 18 + sx + kx) * 32 + o * 8), f);
#pragma unroll
        for (int j = 0; j < 8; ++j) a[j] = fmaf(w3[ky * 3 + kx], f[j], a[j]);
      }
#pragma unroll
    for (int j = 0; j < 8; ++j) {
      const u16 kb16 = f2bf(a[j]);
      const float kv = bf2f(kb16);
      K3s[(o * 8 + j) * 132 + px] = kb16;
      racc[j] = fmaf(kv, kv, racc[j]);
    }
    const uint4 uq = *reinterpret_cast<const uint4*>(
        q3 + ((size_t)((b << 16) + ((y0 + sy) << 8) + x0 + sx)) * 256 + h * 32 + o * 8);
    Q3s[(o * 8 + 0) * 132 + px] = (u16)(uq.x & 0xffffu);
    Q3s[(o * 8 + 1) * 132 + px] = (u16)(uq.x >> 16);
    Q3s[(o * 8 + 2) * 132 + px] = (u16)(uq.y & 0xffffu);
    Q3s[(o * 8 + 3) * 132 + px] = (u16)(uq.y >> 16);
    Q3s[(o * 8 + 4) * 132 + px] = (u16)(uq.z & 0xffffu);
    Q3s[(o * 8 + 5) * 132 + px] = (u16)(uq.z >> 16);
    Q3s[(o * 8 + 6) * 132 + px] = (u16)(uq.w & 0xffffu);
    Q3s[(o * 8 + 7) * 132 + px] = (u16)(uq.w >> 16);
  }
  __syncthreads();
#pragma unroll
  for (int j = 0; j < 8; ++j) atomicAdd(&rbuf[o * 8 + j], racc[j]);
  __syncthreads();
  if (t < 32) atomicAdd(&sqk[b * 256 + h * 32 + t], rbuf[t]);

  const int wave = t >> 6;
  const int lane = t & 63;
  const int quad = lane >> 4;
  const int l15 = lane & 15;
  const int d0 = (wave & 1) * 16;
  const int e0 = (wave >> 1) * 16;
  f32x4_t acc = {0.f, 0.f, 0.f, 0.f};
#pragma unroll
  for (int kb = 0; kb < 4; ++kb) {
    const bf16x8_t av = *reinterpret_cast<const bf16x8_t*>(
        &K3s[(d0 + l15) * 132 + kb * 32 + quad * 8]);
    const bf16x8_t bv = *reinterpret_cast<const bf16x8_t*>(
        &Q3s[(e0 + l15) * 132 + kb * 32 + quad * 8]);
    acc = __builtin_amdgcn_mfma_f32_16x16x32_bf16(av, bv, acc, 0, 0, 0);
  }
  float* Gp = G + (size_t)((b * 8 + h) * 32) * 32;
#pragma unroll
  for (int r = 0; r < 4; ++r)
    atomicAdd(&Gp[(d0 + quad * 4 + r) * 32 + e0 + l15], acc[r]);
}

// ---------------------------------------------------------------------------
// attn finalize: normalize Gram, conv1d diag, softmax.
__global__ __launch_bounds__(256) void attn_kernel(
    const float* __restrict__ G, const float* __restrict__ sqq,
    const float* __restrict__ sqk, const float* __restrict__ vsum,
    const float* __restrict__ cw, const float* __restrict__ cb,
    const float* __restrict__ rs1, const float* __restrict__ rs2,
    float* __restrict__ attn) {
  const int b = blockIdx.x;
  const int t = threadIdx.x;
  const int h = t >> 5;
  const int d = t & 31;
  __shared__ float vm[8][34];
  __shared__ float nq[256];
  vm[h][d + 1] = vsum[b * 256 + t] * (1.0f / 65536.0f);
  if (t < 8) { vm[t][0] = 0.f; vm[t][33] = 0.f; }
  nq[t] = fmaxf(sqrtf(sqq[b * 256 + t]), 1e-12f);
  __syncthreads();

  float av = cb[h];
#pragma unroll
  for (int i = 0; i < 8; ++i)
#pragma unroll
    for (int tau = 0; tau < 3; ++tau)
      av = fmaf(cw[h * 24 + i * 3 + tau], vm[i][d + tau], av);

  const float nk = fmaxf(sqrtf(sqk[b * 256 + t]), 1e-12f);
  const float rsc = rs1[h];
  const float rsc2 = rs2[h];
  const float* Gp = G + (size_t)((b * 8 + h) * 32 + d) * 32;
  float L[32];
#pragma unroll
  for (int e = 0; e < 32; ++e) {
    float l = Gp[e] * rsc / (nk * nq[h * 32 + e]);
    if (e == d) l += av * rsc2;
    L[e] = l;
  }
  float mx = L[0];
#pragma unroll
  for (int e = 1; e < 32; ++e) mx = fmaxf(mx, L[e]);
  float s = 0.f;
#pragma unroll
  for (int e = 0; e < 32; ++e) {
    L[e] = expf(L[e] - mx);
    s += L[e];
  }
  const float inv = 1.0f / s;
  float* Ap = attn + (size_t)((b * 8 + h) * 32 + d) * 32;
#pragma unroll
  for (int e = 0; e < 32; ++e) Ap[e] = L[e] * inv;
}

// M_b[c'][h*32+e] = sum_d proj_w[c'][h*32+d] * attn[b,h,d,e]  (bf16)
__global__ __launch_bounds__(256) void mbuild_kernel(
    const float* __restrict__ attn, const float* __restrict__ pw,
    u16* __restrict__ M) {
  const int bid = blockIdx.x;
  const int b = bid >> 3;
  const int h = bid & 7;
  const int t = threadIdx.x;
  __shared__ float at[32][33];
#pragma unroll
  for (int i = 0; i < 4; ++i) {
    const int idx = t * 4 + i;
    at[idx >> 5][idx & 31] = attn[(size_t)(b * 8 + h) * 1024 + idx];
  }
  __syncthreads();
  float pwf[32];
#pragma unroll
  for (int dd = 0; dd < 32; ++dd) pwf[dd] = pw[(size_t)t * 256 + h * 32 + dd];
  u16* Mp = M + (size_t)b * 65536 + (size_t)t * 256 + h * 32;
#pragma unroll
  for (int e = 0; e < 32; ++e) {
    float s = 0.f;
#pragma unroll
    for (int dd = 0; dd < 32; ++dd) s = fmaf(pwf[dd], at[dd][e], s);
    Mp[e] = f2bf(s);
  }
}

// out[m][c'] = sum_k v3[m][k] * M_b[c'][k] + proj_b[c'].  128x64 tile, fp32 out.
__global__ __launch_bounds__(256) void gemm_kernel(
    const u16* __restrict__ V, const u16* __restrict__ Mm,
    const float* __restrict__ pb, float* __restrict__ out) {
  const int m0 = blockIdx.x * 128;
  const int n0 = blockIdx.y * 64;
  const int b = m0 >> 16;
  const u16* Mb = Mm + (size_t)b * 65536;

  __shared__ __align__(16) u16 As[128][72];
  __shared__ __align__(16) u16 Bs[64][72];

  const int t = threadIdx.x;
  const int wave = t >> 6;
  const int lane = t & 63;
  const int quad = lane >> 4;
  const int l15 = lane & 15;

  f32x4_t acc[2][4];
#pragma unroll
  for (int mt = 0; mt < 2; ++mt)
#pragma unroll
    for (int nt = 0; nt < 4; ++nt) acc[mt][nt] = {0.f, 0.f, 0.f, 0.f};

  for (int k0 = 0; k0 < 256; k0 += 64) {
#pragma unroll
    for (int i = 0; i < 4; ++i) {
      const int id = t + 256 * i;
      const int row = id >> 3;
      const int c8 = id & 7;
      *reinterpret_cast<uint4*>(&As[row][c8 * 8]) = *reinterpret_cast<const uint4*>(
          &V[(size_t)(m0 + row) * 256 + k0 + c8 * 8]);
    }
#pragma unroll
    for (int i = 0; i < 2; ++i) {
      const int id = t + 256 * i;
      const int row = id >> 3;
      const int c8 = id & 7;
      *reinterpret_cast<uint4*>(&Bs[row][c8 * 8]) = *reinterpret_cast<const uint4*>(
          &Mb[(size_t)(n0 + row) * 256 + k0 + c8 * 8]);
    }
    __syncthreads();
#pragma unroll
    for (int ks = 0; ks < 2; ++ks) {
      bf16x8_t af[2], bfv[4];
#pragma unroll
      for (int mt = 0; mt < 2; ++mt)
        af[mt] = *reinterpret_cast<const bf16x8_t*>(
            &As[wave * 32 + mt * 16 + l15][ks * 32 + quad * 8]);
#pragma unroll
      for (int nt = 0; nt < 4; ++nt)
        bfv[nt] = *reinterpret_cast<const bf16x8_t*>(
            &Bs[nt * 16 + l15][ks * 32 + quad * 8]);
#pragma unroll
      for (int mt = 0; mt < 2; ++mt)
#pragma unroll
        for (int nt = 0; nt < 4; ++nt)
          acc[mt][nt] =
              __builtin_amdgcn_mfma_f32_16x16x32_bf16(af[mt], bfv[nt], acc[mt][nt], 0, 0, 0);
    }
    __syncthreads();
  }

#pragma unroll
  for (int nt = 0; nt < 4; ++nt) {
    const int col = n0 + nt * 16 + l15;
    const float pbf = pb[col];
#pragma unroll
    for (int mt = 0; mt < 2; ++mt) {
#pragma unroll
      for (int r = 0; r < 4; ++r) {
        const int m = m0 + wave * 32 + mt * 16 + quad * 4 + r;
        out[(size_t)m * 256 + col] = acc[mt][nt][r] + pbf;
      }
    }
  }
}

extern "C" void kernel_launch(void* const* d_in, const int* in_sizes, int n_in,
                              void* d_out, int out_size, void* d_ws, size_t ws_size,
                              hipStream_t stream) {
  const float* x_in = (const float*)d_in[0];
  const float* qw1 = (const float*)d_in[1];
  const float* qw2 = (const float*)d_in[2];
  const float* qw3 = (const float*)d_in[3];
  const float* kw1 = (const float*)d_in[4];
  const float* kw2 = (const float*)d_in[5];
  const float* kw3 = (const float*)d_in[6];
  const float* vw1 = (const float*)d_in[7];
  const float* vw2 = (const float*)d_in[8];
  const float* vw3 = (const float*)d_in[9];
  const float* posw1 = (const float*)d_in[10];
  const float* posb1 = (const float*)d_in[11];
  const float* posw2 = (const float*)d_in[12];
  const float* posb2 = (const float*)d_in[13];
  const float* cw = (const float*)d_in[14];
  const float* cb = (const float*)d_in[15];
  const float* rs1 = (const float*)d_in[16];
  const float* rs2 = (const float*)d_in[17];
  const float* pw = (const float*)d_in[18];
  const float* pb = (const float*)d_in[19];

  char* ws = (char*)d_ws;
  const size_t SLOT = 67108864;  // one (2,256,256,256) bf16 image
  u16* S0 = (u16*)(ws);            // x2
  u16* S1 = (u16*)(ws + SLOT);     // v3
  u16* D0 = (u16*)d_out;           // q3 (border tiles only; dead before gemm)
  char* SM = ws + 2 * SLOT;
  float* G = (float*)(SM);              // 2*8*32*32 f32
  float* sqq = (float*)(SM + 65536);
  float* sqk = (float*)(SM + 67584);
  float* vsum = (float*)(SM + 69632);
  float* attn = (float*)(SM + 71680);
  u16* Mm = (u16*)(SM + 137216);
  float* Wc = (float*)(SM + 399360);    // composed weights [8][3][49] f32 (4.7KB)

  hipMemsetAsync(SM, 0, 71680, stream);

  compose_kernel<<<1, 64, 0, stream>>>(qw1, qw2, qw3, kw1, kw2, kw3,
                                       vw1, vw2, vw3, Wc);

  const dim3 tgrid(16, 32, 16);
  posemb_kernel<<<tgrid, 256, 0, stream>>>(x_in, S0, posw1, posb1, posw2, posb2);

  // Interior: fused q/k/v composed-7x7 + Gram + reductions (bx 1..14, by 1..30)
  qkv_fused_kernel<<<dim3(14, 30, 16), 256, 0, stream>>>(S0, S1, Wc, G, sqq, sqk, vsum);

  // Border: exact 3-stage path on 92 remapped tile positions
  const dim3 bgrid(92, 1, 16);
  chain3_kernel<1, 1><<<bgrid, 256, 0, stream>>>(S0, D0, qw1, qw2, qw3, sqq);
  kchain_gram_kernel<1><<<bgrid, 256, 0, stream>>>(S0, D0, kw1, kw2, kw3, G, sqk);
  chain3_kernel<2, 1><<<bgrid, 256, 0, stream>>>(S0, S1, vw1, vw2, vw3, vsum);

  attn_kernel<<<2, 256, 0, stream>>>(G, sqq, sqk, vsum, cw, cb, rs1, rs2, attn);
  mbuild_kernel<<<16, 256, 0, stream>>>(attn, pw, Mm);
  gemm_kernel<<<dim3(1024, 4), 256, 0, stream>>>(S1, Mm, pb, (float*)d_out);
}

// Round 8
// 878.639 us; speedup vs baseline: 2.1145x; 1.0280x over previous
//
#include <hip/hip_runtime.h>
#include <stdint.h>
#include <math.h>

// MS_MSA fused pipeline:
//   compose_kernel : Weff[h][chain] = w1*w2*w3 composed 7x7 stencil (fp32, ws)
//   posemb_kernel  : x2 = x + dw2(gelu(dw1(x)+b1))+b2   (2-stage tile fusion)
//   qkv_fused      : INTERIOR tiles (r1-verified structure, 358us @878 total):
//                    joint composed-7x7 sweep for q,k,v, rolled iy loop
//                    (unrolling spills — r5/r6), global s_load weights
//                    (LDS weights were -6%, r7). ONE change vs r1: halo P0
//                    staged via async __builtin_amdgcn_global_load_lds(16B)
//                    — layout is exactly linear (item i -> LDS byte i*16),
//                    kills the VGPR round-trip (m97: compiler never auto-emits).
//   chain3/kchain  : BORDER tiles only (92/512 positions) via exact 3-stage path.
//   attn/mbuild    : softmax + fold proj_w*blockdiag(attn) -> M
//   gemm           : out = v3 @ M_b^T + proj_b  (bf16 MFMA, fp32 out)
// ws: S0=x2, S1=v3 (2 x 64MiB) + smalls + Wc(4.7KB) — layout == verified r1.
// d_out scratch: [0,64MiB) q3 (border tiles only; dead before gemm).

using u16 = unsigned short;
using u32 = unsigned int;

typedef __bf16 bf16x8_t __attribute__((ext_vector_type(8)));
typedef float f32x4_t __attribute__((ext_vector_type(4)));

__device__ __forceinline__ float bf2f(u16 v) {
  u32 u = ((u32)v) << 16;
  return __builtin_bit_cast(float, u);
}
__device__ __forceinline__ u16 f2bf(float f) {
  u32 u = __builtin_bit_cast(u32, f);
  u32 r = u + 0x7fffu + ((u >> 16) & 1u);  // RNE (finite inputs)
  return (u16)(r >> 16);
}
__device__ __forceinline__ void unpack8(uint4 u, float f[8]) {
  f[0] = bf2f((u16)(u.x & 0xffffu)); f[1] = bf2f((u16)(u.x >> 16));
  f[2] = bf2f((u16)(u.y & 0xffffu)); f[3] = bf2f((u16)(u.y >> 16));
  f[4] = bf2f((u16)(u.z & 0xffffu)); f[5] = bf2f((u16)(u.z >> 16));
  f[6] = bf2f((u16)(u.w & 0xffffu)); f[7] = bf2f((u16)(u.w >> 16));
}
__device__ __forceinline__ uint4 pack8(const u16 o[8]) {
  uint4 v;
  v.x = (u32)o[0] | ((u32)o[1] << 16);
  v.y = (u32)o[2] | ((u32)o[3] << 16);
  v.z = (u32)o[4] | ((u32)o[5] << 16);
  v.w = (u32)o[6] | ((u32)o[7] << 16);
  return v;
}
// async global->LDS DMA, 16B per lane; lds dst must be wave-uniform base
// (HW adds lane*16). Compiler inserts vmcnt(0) before the next s_barrier.
__device__ __forceinline__ void gload_lds16(const void* g, void* l) {
  __builtin_amdgcn_global_load_lds(
      (const __attribute__((address_space(1))) void*)g,
      (__attribute__((address_space(3))) void*)l, 16, 0, 0);
}

// ---------------------------------------------------------------------------
// compose: Weff = w1 (*) w2 (*) w3 (kernel-array convolution; correlation
// offsets add). Wc[h][c][dy*7+dx], c: 0=q,1=k,2=v. 24 active threads.
__global__ __launch_bounds__(64) void compose_kernel(
    const float* __restrict__ qw1, const float* __restrict__ qw2,
    const float* __restrict__ qw3, const float* __restrict__ kw1,
    const float* __restrict__ kw2, const float* __restrict__ kw3,
    const float* __restrict__ vw1, const float* __restrict__ vw2,
    const float* __restrict__ vw3, float* __restrict__ Wc) {
  const int t = threadIdx.x;
  if (t >= 24) return;
  const int h = t / 3, c = t % 3;
  const float* w1 = (c == 0 ? qw1 : c == 1 ? kw1 : vw1) + h * 9;
  const float* w2 = (c == 0 ? qw2 : c == 1 ? kw2 : vw2) + h * 9;
  const float* w3 = (c == 0 ? qw3 : c == 1 ? kw3 : vw3) + h * 9;
  float w12[25];
  for (int i = 0; i < 25; ++i) w12[i] = 0.f;
  for (int ky = 0; ky < 3; ++ky)
    for (int kx = 0; kx < 3; ++kx)
      for (int ly = 0; ly < 3; ++ly)
        for (int lx = 0; lx < 3; ++lx)
          w12[(ky + ly) * 5 + kx + lx] += w2[ky * 3 + kx] * w1[ly * 3 + lx];
  float we[49];
  for (int i = 0; i < 49; ++i) we[i] = 0.f;
  for (int my = 0; my < 3; ++my)
    for (int mx = 0; mx < 3; ++mx)
      for (int ey = 0; ey < 5; ++ey)
        for (int ex = 0; ex < 5; ++ex)
          we[(my + ey) * 7 + mx + ex] += w3[my * 3 + mx] * w12[ey * 5 + ex];
  float* dst = Wc + (h * 3 + c) * 49;
  for (int i = 0; i < 49; ++i) dst[i] = we[i];
}

// ---------------------------------------------------------------------------
// posemb: 2-stage fused, per-channel weights, fp32 input, gelu, residual.
__global__ __launch_bounds__(256) void posemb_kernel(
    const float* __restrict__ xin, u16* __restrict__ x2,
    const float* __restrict__ w1g, const float* __restrict__ b1g,
    const float* __restrict__ w2g, const float* __restrict__ b2g) {
  const int t = threadIdx.x;
  const int o = t & 3;
  const int bz = blockIdx.z;
  const int cg = bz & 7;
  const int b = bz >> 3;
  const int x0 = blockIdx.x * 16;
  const int y0 = blockIdx.y * 8;
  const int c0 = cg * 32 + o * 8;

  __shared__ __align__(16) u16 Abuf[240 * 32];
  __shared__ __align__(16) u16 Bbuf[180 * 32];

  for (int i = t; i < 240 * 4; i += 256) {
    const int px = i >> 2, oo = i & 3;
    const int lx = px % 20, ly = px / 20;
    const int gx = x0 - 2 + lx, gy = y0 - 2 + ly;
    u16 ov[8];
    if (gx >= 0 && gx < 256 && gy >= 0 && gy < 256) {
      const float* p = xin + ((size_t)((b << 16) + (gy << 8) + gx)) * 256 + cg * 32 + oo * 8;
      const float4 r0 = *reinterpret_cast<const float4*>(p);
      const float4 r1 = *reinterpret_cast<const float4*>(p + 4);
      ov[0] = f2bf(r0.x); ov[1] = f2bf(r0.y); ov[2] = f2bf(r0.z); ov[3] = f2bf(r0.w);
      ov[4] = f2bf(r1.x); ov[5] = f2bf(r1.y); ov[6] = f2bf(r1.z); ov[7] = f2bf(r1.w);
    } else {
#pragma unroll
      for (int j = 0; j < 8; ++j) ov[j] = 0;
    }
    *reinterpret_cast<uint4*>(Abuf + px * 32 + oo * 8) = pack8(ov);
  }
  __syncthreads();

  {
    float w[72], bi[8];
#pragma unroll
    for (int j = 0; j < 8; ++j) {
#pragma unroll
      for (int k = 0; k < 9; ++k) w[j * 9 + k] = w1g[(c0 + j) * 9 + k];
      bi[j] = b1g[c0 + j];
    }
    for (int i = t; i < 180 * 4; i += 256) {
      const int px = i >> 2;
      const int sx = px % 18, sy = px / 18;
      const int gx = x0 - 1 + sx, gy = y0 - 1 + sy;
      const bool inb = (gx >= 0 && gx < 256 && gy >= 0 && gy < 256);
      float a[8];
#pragma unroll
      for (int j = 0; j < 8; ++j) a[j] = bi[j];
#pragma unroll
      for (int ky = 0; ky < 3; ++ky)
#pragma unroll
        for (int kx = 0; kx < 3; ++kx) {
          float f[8];
          unpack8(*reinterpret_cast<const uint4*>(
                      Abuf + ((sy + ky) * 20 + sx + kx) * 32 + o * 8), f);
#pragma unroll
          for (int j = 0; j < 8; ++j) a[j] = fmaf(w[j * 9 + ky * 3 + kx], f[j], a[j]);
        }
      u16 ov[8];
#pragma unroll
      for (int j = 0; j < 8; ++j) {
        const float g = 0.5f * a[j] * (1.0f + erff(a[j] * 0.70710678118654752f));
        ov[j] = inb ? f2bf(g) : (u16)0;
      }
      *reinterpret_cast<uint4*>(Bbuf + px * 32 + o * 8) = pack8(ov);
    }
  }
  __syncthreads();

  {
    float w[72], bi[8];
#pragma unroll
    for (int j = 0; j < 8; ++j) {
#pragma unroll
      for (int k = 0; k < 9; ++k) w[j * 9 + k] = w2g[(c0 + j) * 9 + k];
      bi[j] = b2g[c0 + j];
    }
    for (int i = t; i < 128 * 4; i += 256) {
      const int px = i >> 2;
      const int sx = px & 15, sy = px >> 4;
      float a[8];
#pragma unroll
      for (int j = 0; j < 8; ++j) a[j] = bi[j];
#pragma unroll
      for (int ky = 0; ky < 3; ++ky)
#pragma unroll
        for (int kx = 0; kx < 3; ++kx) {
          float f[8];
          unpack8(*reinterpret_cast<const uint4*>(
                      Bbuf + ((sy + ky) * 18 + sx + kx) * 32 + o * 8), f);
#pragma unroll
          for (int j = 0; j < 8; ++j) a[j] = fmaf(w[j * 9 + ky * 3 + kx], f[j], a[j]);
        }
      float xr[8];
      unpack8(*reinterpret_cast<const uint4*>(
                  Abuf + ((sy + 2) * 20 + sx + 2) * 32 + o * 8), xr);
      u16 ov[8];
#pragma unroll
      for (int j = 0; j < 8; ++j) ov[j] = f2bf(a[j] + xr[j]);
      u16* dst = x2 + ((size_t)((b << 16) + ((y0 + sy) << 8) + x0 + sx)) * 256 + cg * 32 + o * 8;
      *reinterpret_cast<uint4*>(dst) = pack8(ov);
    }
  }
}

// ---------------------------------------------------------------------------
// qkv_fused: interior tiles only (bx 1..14, by 1..30 of the 16x8 tiling).
// One 22x14 halo load (async DMA); joint composed-7x7 sweep for q,k,v.
// Weights read per-iteration from global Wc (wave-uniform -> s_load; r1 path).
// iy loop rolled (unroll -> spill). Epilogue: Gram MFMA (staging aliases dead
// Abuf), reductions, v3 store. Thread: o=t&3 (8 ch), sx=(t>>2)&15, yg=t>>6.
__global__ __launch_bounds__(256) void qkv_fused_kernel(
    const u16* __restrict__ x2, u16* __restrict__ v3out,
    const float* __restrict__ Wc, float* __restrict__ G,
    float* __restrict__ sqq, float* __restrict__ sqk,
    float* __restrict__ vsum) {
  const int t = threadIdx.x;
  const int o = t & 3;
  const int sx = (t >> 2) & 15;
  const int yg = t >> 6;
  const int bz = blockIdx.z;
  const int h = bz & 7;
  const int b = bz >> 3;
  const int x0 = (blockIdx.x + 1) * 16;
  const int y0 = (blockIdx.y + 1) * 8;

  __shared__ __align__(16) u16 Abuf[308 * 32];  // halo 22x14; later K3s/Q3s
  __shared__ float rbuf[96];
  if (t < 96) rbuf[t] = 0.f;

  // P0: halo via async global->LDS DMA. Item i (16B) -> LDS byte i*16 (linear:
  // px*64 + oo*16 = i*16). Items 0..1023: 4 full-wave DMA iterations with
  // wave-uniform LDS base (HW adds lane*16). 208-item tail: regular path.
  {
    const int wv = t >> 6;
#pragma unroll
    for (int it = 0; it < 4; ++it) {
      const int i = it * 256 + t;
      const int px = i >> 2, oo = i & 3;
      const int lx = px % 22, ly = px / 22;
      const int gx = x0 - 3 + lx, gy = y0 - 3 + ly;
      const u16* gsrc =
          x2 + ((size_t)((b << 16) + (gy << 8) + gx)) * 256 + h * 32 + oo * 8;
      u16* ldst = Abuf + (size_t)(it * 256 + wv * 64) * 8;  // wave-uniform base
      gload_lds16(gsrc, ldst);
    }
    if (t < 208) {
      const int i = 1024 + t;
      const int px = i >> 2, oo = i & 3;
      const int lx = px % 22, ly = px / 22;
      const int gx = x0 - 3 + lx, gy = y0 - 3 + ly;
      *reinterpret_cast<uint4*>(Abuf + px * 32 + oo * 8) =
          *reinterpret_cast<const uint4*>(
              x2 + ((size_t)((b << 16) + (gy << 8) + gx)) * 256 + h * 32 + oo * 8);
    }
  }
  __syncthreads();

  const float* Wq = Wc + (h * 3 + 0) * 49;
  const float* Wk = Wc + (h * 3 + 1) * 49;
  const float* Wv = Wc + (h * 3 + 2) * 49;

  float aq[2][8], ak[2][8], av2[2][8];
#pragma unroll
  for (int r = 0; r < 2; ++r)
#pragma unroll
    for (int j = 0; j < 8; ++j) { aq[r][j] = 0.f; ak[r][j] = 0.f; av2[r][j] = 0.f; }

  const int ty0 = yg * 2;
  const u16* Arow0 = Abuf + (ty0 * 22 + sx) * 32 + o * 8;

  // iy = 0: serves ry=0 only (dy=0)
  {
    const u16* Ar = Arow0;
#pragma unroll
    for (int jx = 0; jx < 7; ++jx) {
      float f[8];
      unpack8(*reinterpret_cast<const uint4*>(Ar + jx * 32), f);
      const float wq = Wq[jx], wk = Wk[jx], wv = Wv[jx];
#pragma unroll
      for (int j = 0; j < 8; ++j) {
        aq[0][j] = fmaf(wq, f[j], aq[0][j]);
        ak[0][j] = fmaf(wk, f[j], ak[0][j]);
        av2[0][j] = fmaf(wv, f[j], av2[0][j]);
      }
    }
  }
  // iy = 1..6: serves ry=0 (dy=iy) and ry=1 (dy=iy-1). Rolled (unroll -> spill).
#pragma unroll 1
  for (int iy = 1; iy <= 6; ++iy) {
    const u16* Ar = Arow0 + iy * (22 * 32);
    const float* wq0 = Wq + iy * 7;
    const float* wk0 = Wk + iy * 7;
    const float* wv0 = Wv + iy * 7;
#pragma unroll
    for (int jx = 0; jx < 7; ++jx) {
      float f[8];
      unpack8(*reinterpret_cast<const uint4*>(Ar + jx * 32), f);
      float w;
      w = wq0[jx];
#pragma unroll
      for (int j = 0; j < 8; ++j) aq[0][j] = fmaf(w, f[j], aq[0][j]);
      w = wq0[jx - 7];
#pragma unroll
      for (int j = 0; j < 8; ++j) aq[1][j] = fmaf(w, f[j], aq[1][j]);
      w = wk0[jx];
#pragma unroll
      for (int j = 0; j < 8; ++j) ak[0][j] = fmaf(w, f[j], ak[0][j]);
      w = wk0[jx - 7];
#pragma unroll
      for (int j = 0; j < 8; ++j) ak[1][j] = fmaf(w, f[j], ak[1][j]);
      w = wv0[jx];
#pragma unroll
      for (int j = 0; j < 8; ++j) av2[0][j] = fmaf(w, f[j], av2[0][j]);
      w = wv0[jx - 7];
#pragma unroll
      for (int j = 0; j < 8; ++j) av2[1][j] = fmaf(w, f[j], av2[1][j]);
    }
  }
  // iy = 7: serves ry=1 only (dy=6)
  {
    const u16* Ar = Arow0 + 7 * (22 * 32);
#pragma unroll
    for (int jx = 0; jx < 7; ++jx) {
      float f[8];
      unpack8(*reinterpret_cast<const uint4*>(Ar + jx * 32), f);
      const float wq = Wq[42 + jx], wk = Wk[42 + jx], wv = Wv[42 + jx];
#pragma unroll
      for (int j = 0; j < 8; ++j) {
        aq[1][j] = fmaf(wq, f[j], aq[1][j]);
        ak[1][j] = fmaf(wk, f[j], ak[1][j]);
        av2[1][j] = fmaf(wv, f[j], av2[1][j]);
      }
    }
  }

  __syncthreads();  // all Abuf reads done -> safe to alias staging into it

  u16* K3s = Abuf;             // [32][132]
  u16* Q3s = Abuf + 32 * 132;  // [32][132]

  float rq[8], rk[8], rv[8];
#pragma unroll
  for (int j = 0; j < 8; ++j) { rq[j] = 0.f; rk[j] = 0.f; rv[j] = 0.f; }
#pragma unroll
  for (int ry = 0; ry < 2; ++ry) {
    const int px = (ty0 + ry) * 16 + sx;
    u16 ov[8];
#pragma unroll
    for (int j = 0; j < 8; ++j) {
      const u16 qb = f2bf(aq[ry][j]);
      Q3s[(o * 8 + j) * 132 + px] = qb;
      const float qf = bf2f(qb);
      rq[j] = fmaf(qf, qf, rq[j]);
      const u16 kb = f2bf(ak[ry][j]);
      K3s[(o * 8 + j) * 132 + px] = kb;
      const float kf = bf2f(kb);
      rk[j] = fmaf(kf, kf, rk[j]);
      ov[j] = f2bf(av2[ry][j]);
      rv[j] += bf2f(ov[j]);
    }
    u16* dst = v3out + ((size_t)((b << 16) + ((y0 + ty0 + ry) << 8) + x0 + sx)) * 256 + h * 32 + o * 8;
    *reinterpret_cast<uint4*>(dst) = pack8(ov);
  }
#pragma unroll
  for (int j = 0; j < 8; ++j) {
    atomicAdd(&rbuf[o * 8 + j], rq[j]);
    atomicAdd(&rbuf[32 + o * 8 + j], rk[j]);
    atomicAdd(&rbuf[64 + o * 8 + j], rv[j]);
  }
  __syncthreads();

  // Gram MFMA: wave -> 16x16 quadrant, K=128 (whole tile)
  const int wave = t >> 6;
  const int lane = t & 63;
  const int quad = lane >> 4;
  const int l15 = lane & 15;
  const int d0 = (wave & 1) * 16;
  const int e0 = (wave >> 1) * 16;
  f32x4_t acc = {0.f, 0.f, 0.f, 0.f};
#pragma unroll
  for (int kb = 0; kb < 4; ++kb) {
    const bf16x8_t avf = *reinterpret_cast<const bf16x8_t*>(
        &K3s[(d0 + l15) * 132 + kb * 32 + quad * 8]);
    const bf16x8_t bvf = *reinterpret_cast<const bf16x8_t*>(
        &Q3s[(e0 + l15) * 132 + kb * 32 + quad * 8]);
    acc = __builtin_amdgcn_mfma_f32_16x16x32_bf16(avf, bvf, acc, 0, 0, 0);
  }
  float* Gp = G + (size_t)((b * 8 + h) * 32) * 32;
#pragma unroll
  for (int r = 0; r < 4; ++r)
    atomicAdd(&Gp[(d0 + quad * 4 + r) * 32 + e0 + l15], acc[r]);

  if (t < 32) atomicAdd(&sqq[b * 256 + h * 32 + t], rbuf[t]);
  else if (t < 64) atomicAdd(&sqk[b * 256 + h * 32 + (t - 32)], rbuf[t]);
  else if (t < 96) atomicAdd(&vsum[b * 256 + h * 32 + (t - 64)], rbuf[t]);
}

// ---------------------------------------------------------------------------
// Border block-index remap: 92 positions.
__device__ __forceinline__ void border_map(int bi, int& bx, int& by) {
  if (bi < 16) { bx = bi; by = 0; }
  else if (bi < 32) { bx = bi - 16; by = 31; }
  else { const int e = bi - 32; by = 1 + (e >> 1); bx = (e & 1) * 15; }
}

// ---------------------------------------------------------------------------
// chain3: exact 3-stage path, BORDER grid (92,1,16). RED: 1=sumsq, 2=sum.
template <int RED, int BORDER>
__global__ __launch_bounds__(256) void chain3_kernel(
    const u16* __restrict__ in, u16* __restrict__ out,
    const float* __restrict__ w1g, const float* __restrict__ w2g,
    const float* __restrict__ w3g, float* __restrict__ red) {
  const int t = threadIdx.x;
  const int o = t & 3;
  const int bz = blockIdx.z;
  const int h = bz & 7;
  const int b = bz >> 3;
  int bx = blockIdx.x, by = blockIdx.y;
  if (BORDER) border_map(blockIdx.x, bx, by);
  const int x0 = bx * 16;
  const int y0 = by * 8;

  __shared__ __align__(16) u16 Abuf[308 * 32];
  __shared__ __align__(16) u16 Bbuf[240 * 32];
  __shared__ float rbuf[32];
  if (t < 32) rbuf[t] = 0.f;

  float w1[9], w2[9], w3[9];
#pragma unroll
  for (int k = 0; k < 9; ++k) {
    w1[k] = w1g[h * 9 + k];
    w2[k] = w2g[h * 9 + k];
    w3[k] = w3g[h * 9 + k];
  }

  for (int i = t; i < 308 * 4; i += 256) {
    const int px = i >> 2, oo = i & 3;
    const int lx = px % 22, ly = px / 22;
    const int gx = x0 - 3 + lx, gy = y0 - 3 + ly;
    uint4 v = {0, 0, 0, 0};
    if (gx >= 0 && gx < 256 && gy >= 0 && gy < 256)
      v = *reinterpret_cast<const uint4*>(
          in + ((size_t)((b << 16) + (gy << 8) + gx)) * 256 + h * 32 + oo * 8);
    *reinterpret_cast<uint4*>(Abuf + px * 32 + oo * 8) = v;
  }
  __syncthreads();

  for (int i = t; i < 240 * 4; i += 256) {
    const int px = i >> 2;
    const int sx = px % 20, sy = px / 20;
    const int gx = x0 - 2 + sx, gy = y0 - 2 + sy;
    const bool inb = (gx >= 0 && gx < 256 && gy >= 0 && gy < 256);
    float a[8] = {0, 0, 0, 0, 0, 0, 0, 0};
#pragma unroll
    for (int ky = 0; ky < 3; ++ky)
#pragma unroll
      for (int kx = 0; kx < 3; ++kx) {
        float f[8];
        unpack8(*reinterpret_cast<const uint4*>(
                    Abuf + ((sy + ky) * 22 + sx + kx) * 32 + o * 8), f);
#pragma unroll
        for (int j = 0; j < 8; ++j) a[j] = fmaf(w1[ky * 3 + kx], f[j], a[j]);
      }
    u16 ov[8];
#pragma unroll
    for (int j = 0; j < 8; ++j) ov[j] = inb ? f2bf(a[j]) : (u16)0;
    *reinterpret_cast<uint4*>(Bbuf + px * 32 + o * 8) = pack8(ov);
  }
  __syncthreads();

  for (int i = t; i < 180 * 4; i += 256) {
    const int px = i >> 2;
    const int sx = px % 18, sy = px / 18;
    const int gx = x0 - 1 + sx, gy = y0 - 1 + sy;
    const bool inb = (gx >= 0 && gx < 256 && gy >= 0 && gy < 256);
    float a[8] = {0, 0, 0, 0, 0, 0, 0, 0};
#pragma unroll
    for (int ky = 0; ky < 3; ++ky)
#pragma unroll
      for (int kx = 0; kx < 3; ++kx) {
        float f[8];
        unpack8(*reinterpret_cast<const uint4*>(
                    Bbuf + ((sy + ky) * 20 + sx + kx) * 32 + o * 8), f);
#pragma unroll
        for (int j = 0; j < 8; ++j) a[j] = fmaf(w2[ky * 3 + kx], f[j], a[j]);
      }
    u16 ov[8];
#pragma unroll
    for (int j = 0; j < 8; ++j) ov[j] = inb ? f2bf(a[j]) : (u16)0;
    *reinterpret_cast<uint4*>(Abuf + px * 32 + o * 8) = pack8(ov);
  }
  __syncthreads();

  float racc[8] = {0, 0, 0, 0, 0, 0, 0, 0};
  for (int i = t; i < 128 * 4; i += 256) {
    const int px = i >> 2;
    const int sx = px & 15, sy = px >> 4;
    float a[8] = {0, 0, 0, 0, 0, 0, 0, 0};
#pragma unroll
    for (int ky = 0; ky < 3; ++ky)
#pragma unroll
      for (int kx = 0; kx < 3; ++kx) {
        float f[8];
        unpack8(*reinterpret_cast<const uint4*>(
                    Abuf + ((sy + ky) * 18 + sx + kx) * 32 + o * 8), f);
#pragma unroll
        for (int j = 0; j < 8; ++j) a[j] = fmaf(w3[ky * 3 + kx], f[j], a[j]);
      }
    u16 ov[8];
#pragma unroll
    for (int j = 0; j < 8; ++j) {
      ov[j] = f2bf(a[j]);
      const float rv = bf2f(ov[j]);
      if (RED == 1) racc[j] = fmaf(rv, rv, racc[j]);
      if (RED == 2) racc[j] += rv;
    }
    u16* dst = out + ((size_t)((b << 16) + ((y0 + sy) << 8) + x0 + sx)) * 256 + h * 32 + o * 8;
    *reinterpret_cast<uint4*>(dst) = pack8(ov);
  }
  __syncthreads();
#pragma unroll
  for (int j = 0; j < 8; ++j) atomicAdd(&rbuf[o * 8 + j], racc[j]);
  __syncthreads();
  if (t < 32) atomicAdd(&red[b * 256 + h * 32 + t], rbuf[t]);
}

// ---------------------------------------------------------------------------
// kchain_gram: exact k chain fused with Gram vs q3 tile; BORDER grid only.
template <int BORDER>
__global__ __launch_bounds__(256) void kchain_gram_kernel(
    const u16* __restrict__ in, const u16* __restrict__ q3,
    const float* __restrict__ w1g, const float* __restrict__ w2g,
    const float* __restrict__ w3g, float* __restrict__ G, float* __restrict__ sqk) {
  const int t = threadIdx.x;
  const int o = t & 3;
  const int bz = blockIdx.z;
  const int h = bz & 7;
  const int b = bz >> 3;
  int bx = blockIdx.x, by = blockIdx.y;
  if (BORDER) border_map(blockIdx.x, bx, by);
  const int x0 = bx * 16;
  const int y0 = by * 8;

  __shared__ __align__(16) u16 Abuf[308 * 32];
  __shared__ __align__(16) u16 Bbuf[240 * 32];
  __shared__ __align__(16) u16 K3s[32 * 132];
  __shared__ __align__(16) u16 Q3s[32 * 132];
  __shared__ float rbuf[32];
  if (t < 32) rbuf[t] = 0.f;

  float w1[9], w2[9], w3[9];
#pragma unroll
  for (int k = 0; k < 9; ++k) {
    w1[k] = w1g[h * 9 + k];
    w2[k] = w2g[h * 9 + k];
    w3[k] = w3g[h * 9 + k];
  }

  for (int i = t; i < 308 * 4; i += 256) {
    const int px = i >> 2, oo = i & 3;
    const int lx = px % 22, ly = px / 22;
    const int gx = x0 - 3 + lx, gy = y0 - 3 + ly;
    uint4 v = {0, 0, 0, 0};
    if (gx >= 0 && gx < 256 && gy >= 0 && gy < 256)
      v = *reinterpret_cast<const uint4*>(
          in + ((size_t)((b << 16) + (gy << 8) + gx)) * 256 + h * 32 + oo * 8);
    *reinterpret_cast<uint4*>(Abuf + px * 32 + oo * 8) = v;
  }
  __syncthreads();

  for (int i = t; i < 240 * 4; i += 256) {
    const int px = i >> 2;
    const int sx = px % 20, sy = px / 20;
    const int gx = x0 - 2 + sx, gy = y0 - 2 + sy;
    const bool inb = (gx >= 0 && gx < 256 && gy >= 0 && gy < 256);
    float a[8] = {0, 0, 0, 0, 0, 0, 0, 0};
#pragma unroll
    for (int ky = 0; ky < 3; ++ky)
#pragma unroll
      for (int kx = 0; kx < 3; ++kx) {
        float f[8];
        unpack8(*reinterpret_cast<const uint4*>(
                    Abuf + ((sy + ky) * 22 + sx + kx) * 32 + o * 8), f);
#pragma unroll
        for (int j = 0; j < 8; ++j) a[j] = fmaf(w1[ky * 3 + kx], f[j], a[j]);
      }
    u16 ov[8];
#pragma unroll
    for (int j = 0; j < 8; ++j) ov[j] = inb ? f2bf(a[j]) : (u16)0;
    *reinterpret_cast<uint4*>(Bbuf + px * 32 + o * 8) = pack8(ov);
  }
  __syncthreads();

  for (int i = t; i < 180 * 4; i += 256) {
    const int px = i >> 2;
    const int sx = px % 18, sy = px / 18;
    const int gx = x0 - 1 + sx, gy = y0 - 1 + sy;
    const bool inb = (gx >= 0 && gx < 256 && gy >= 0 && gy < 256);
    float a[8] = {0, 0, 0, 0, 0, 0, 0, 0};
#pragma unroll
    for (int ky = 0; ky < 3; ++ky)
#pragma unroll
      for (int kx = 0; kx < 3; ++kx) {
        float f[8];
        unpack8(*reinterpret_cast<const uint4*>(
                    Bbuf + ((sy + ky) * 20 + sx + kx) * 32 + o * 8), f);
#pragma unroll
        for (int j = 0; j < 8; ++j) a[j] = fmaf(w2[ky * 3 + kx], f[j], a[j]);
      }
    u16 ov[8];
#pragma unroll
    for (int j = 0; j < 8; ++j) ov[j] = inb ? f2bf(a[j]) : (u16)0;
    *reinterpret_cast<uint4*>(Abuf + px * 32 + o * 8) = pack8(ov);
  }
  __syncthreads();

  float racc[8] = {0, 0, 0, 0, 0, 0, 0, 0};
  for (int i = t; i < 128 * 4; i += 256) {
    const int px = i >> 2;
    const int sx = px & 15, sy = px >> 4;
    float a[8] = {0, 0, 0, 0, 0, 0, 0, 0};
#pragma unroll
    for (int ky = 0; ky < 3; ++ky)
#pragma unroll
      for (int kx = 0; kx < 3; ++kx) {
        float f[8];
        unpack8(*reinterpret_cast<const uint4*>(
                    Abuf + ((sy + ky) * 18 + sx + kx) * 32 + o * 8), f);
#pragma unroll
        for (int j = 0; j < 8; ++j) a[j] = fmaf(w3[ky * 3 + kx], f[j], a[j]);
      }
#pragma unroll
    for (int j = 0; j < 8; ++j) {
      const u16 kb16 = f2bf(a[j]);
      const float kv = bf2f(kb16);
      K3s[(o * 8 + j) * 132 + px] = kb16;
      racc[j] = fmaf(kv, kv, racc[j]);
    }
    const uint4 uq = *reinterpret_cast<const uint4*>(
        q3 + ((size_t)((b << 16) + ((y0 + sy) << 8) + x0 + sx)) * 256 + h * 32 + o * 8);
    Q3s[(o * 8 + 0) * 132 + px] = (u16)(uq.x & 0xffffu);
    Q3s[(o * 8 + 1) * 132 + px] = (u16)(uq.x >> 16);
    Q3s[(o * 8 + 2) * 132 + px] = (u16)(uq.y & 0xffffu);
    Q3s[(o * 8 + 3) * 132 + px] = (u16)(uq.y >> 16);
    Q3s[(o * 8 + 4) * 132 + px] = (u16)(uq.z & 0xffffu);
    Q3s[(o * 8 + 5) * 132 + px] = (u16)(uq.z >> 16);
    Q3s[(o * 8 + 6) * 132 + px] = (u16)(uq.w & 0xffffu);
    Q3s[(o * 8 + 7) * 132 + px] = (u16)(uq.w >> 16);
  }
  __syncthreads();
#pragma unroll
  for (int j = 0; j < 8; ++j) atomicAdd(&rbuf[o * 8 + j], racc[j]);
  __syncthreads();
  if (t < 32) atomicAdd(&sqk[b * 256 + h * 32 + t], rbuf[t]);

  const int wave = t >> 6;
  const int lane = t & 63;
  const int quad = lane >> 4;
  const int l15 = lane & 15;
  const int d0 = (wave & 1) * 16;
  const int e0 = (wave >> 1) * 16;
  f32x4_t acc = {0.f, 0.f, 0.f, 0.f};
#pragma unroll
  for (int kb = 0; kb < 4; ++kb) {
    const bf16x8_t av = *reinterpret_cast<const bf16x8_t*>(
        &K3s[(d0 + l15) * 132 + kb * 32 + quad * 8]);
    const bf16x8_t bv = *reinterpret_cast<const bf16x8_t*>(
        &Q3s[(e0 + l15) * 132 + kb * 32 + quad * 8]);
    acc = __builtin_amdgcn_mfma_f32_16x16x32_bf16(av, bv, acc, 0, 0, 0);
  }
  float* Gp = G + (size_t)((b * 8 + h) * 32) * 32;
#pragma unroll
  for (int r = 0; r < 4; ++r)
    atomicAdd(&Gp[(d0 + quad * 4 + r) * 32 + e0 + l15], acc[r]);
}

// ---------------------------------------------------------------------------
// attn finalize: normalize Gram, conv1d diag, softmax.
__global__ __launch_bounds__(256) void attn_kernel(
    const float* __restrict__ G, const float* __restrict__ sqq,
    const float* __restrict__ sqk, const float* __restrict__ vsum,
    const float* __restrict__ cw, const float* __restrict__ cb,
    const float* __restrict__ rs1, const float* __restrict__ rs2,
    float* __restrict__ attn) {
  const int b = blockIdx.x;
  const int t = threadIdx.x;
  const int h = t >> 5;
  const int d = t & 31;
  __shared__ float vm[8][34];
  __shared__ float nq[256];
  vm[h][d + 1] = vsum[b * 256 + t] * (1.0f / 65536.0f);
  if (t < 8) { vm[t][0] = 0.f; vm[t][33] = 0.f; }
  nq[t] = fmaxf(sqrtf(sqq[b * 256 + t]), 1e-12f);
  __syncthreads();

  float av = cb[h];
#pragma unroll
  for (int i = 0; i < 8; ++i)
#pragma unroll
    for (int tau = 0; tau < 3; ++tau)
      av = fmaf(cw[h * 24 + i * 3 + tau], vm[i][d + tau], av);

  const float nk = fmaxf(sqrtf(sqk[b * 256 + t]), 1e-12f);
  const float rsc = rs1[h];
  const float rsc2 = rs2[h];
  const float* Gp = G + (size_t)((b * 8 + h) * 32 + d) * 32;
  float L[32];
#pragma unroll
  for (int e = 0; e < 32; ++e) {
    float l = Gp[e] * rsc / (nk * nq[h * 32 + e]);
    if (e == d) l += av * rsc2;
    L[e] = l;
  }
  float mx = L[0];
#pragma unroll
  for (int e = 1; e < 32; ++e) mx = fmaxf(mx, L[e]);
  float s = 0.f;
#pragma unroll
  for (int e = 0; e < 32; ++e) {
    L[e] = expf(L[e] - mx);
    s += L[e];
  }
  const float inv = 1.0f / s;
  float* Ap = attn + (size_t)((b * 8 + h) * 32 + d) * 32;
#pragma unroll
  for (int e = 0; e < 32; ++e) Ap[e] = L[e] * inv;
}

// M_b[c'][h*32+e] = sum_d proj_w[c'][h*32+d] * attn[b,h,d,e]  (bf16)
__global__ __launch_bounds__(256) void mbuild_kernel(
    const float* __restrict__ attn, const float* __restrict__ pw,
    u16* __restrict__ M) {
  const int bid = blockIdx.x;
  const int b = bid >> 3;
  const int h = bid & 7;
  const int t = threadIdx.x;
  __shared__ float at[32][33];
#pragma unroll
  for (int i = 0; i < 4; ++i) {
    const int idx = t * 4 + i;
    at[idx >> 5][idx & 31] = attn[(size_t)(b * 8 + h) * 1024 + idx];
  }
  __syncthreads();
  float pwf[32];
#pragma unroll
  for (int dd = 0; dd < 32; ++dd) pwf[dd] = pw[(size_t)t * 256 + h * 32 + dd];
  u16* Mp = M + (size_t)b * 65536 + (size_t)t * 256 + h * 32;
#pragma unroll
  for (int e = 0; e < 32; ++e) {
    float s = 0.f;
#pragma unroll
    for (int dd = 0; dd < 32; ++dd) s = fmaf(pwf[dd], at[dd][e], s);
    Mp[e] = f2bf(s);
  }
}

// out[m][c'] = sum_k v3[m][k] * M_b[c'][k] + proj_b[c'].  128x64 tile, fp32 out.
__global__ __launch_bounds__(256) void gemm_kernel(
    const u16* __restrict__ V, const u16* __restrict__ Mm,
    const float* __restrict__ pb, float* __restrict__ out) {
  const int m0 = blockIdx.x * 128;
  const int n0 = blockIdx.y * 64;
  const int b = m0 >> 16;
  const u16* Mb = Mm + (size_t)b * 65536;

  __shared__ __align__(16) u16 As[128][72];
  __shared__ __align__(16) u16 Bs[64][72];

  const int t = threadIdx.x;
  const int wave = t >> 6;
  const int lane = t & 63;
  const int quad = lane >> 4;
  const int l15 = lane & 15;

  f32x4_t acc[2][4];
#pragma unroll
  for (int mt = 0; mt < 2; ++mt)
#pragma unroll
    for (int nt = 0; nt < 4; ++nt) acc[mt][nt] = {0.f, 0.f, 0.f, 0.f};

  for (int k0 = 0; k0 < 256; k0 += 64) {
#pragma unroll
    for (int i = 0; i < 4; ++i) {
      const int id = t + 256 * i;
      const int row = id >> 3;
      const int c8 = id & 7;
      *reinterpret_cast<uint4*>(&As[row][c8 * 8]) = *reinterpret_cast<const uint4*>(
          &V[(size_t)(m0 + row) * 256 + k0 + c8 * 8]);
    }
#pragma unroll
    for (int i = 0; i < 2; ++i) {
      const int id = t + 256 * i;
      const int row = id >> 3;
      const int c8 = id & 7;
      *reinterpret_cast<uint4*>(&Bs[row][c8 * 8]) = *reinterpret_cast<const uint4*>(
          &Mb[(size_t)(n0 + row) * 256 + k0 + c8 * 8]);
    }
    __syncthreads();
#pragma unroll
    for (int ks = 0; ks < 2; ++ks) {
      bf16x8_t af[2], bfv[4];
#pragma unroll
      for (int mt = 0; mt < 2; ++mt)
        af[mt] = *reinterpret_cast<const bf16x8_t*>(
            &As[wave * 32 + mt * 16 + l15][ks * 32 + quad * 8]);
#pragma unroll
      for (int nt = 0; nt < 4; ++nt)
        bfv[nt] = *reinterpret_cast<const bf16x8_t*>(
            &Bs[nt * 16 + l15][ks * 32 + quad * 8]);
#pragma unroll
      for (int mt = 0; mt < 2; ++mt)
#pragma unroll
        for (int nt = 0; nt < 4; ++nt)
          acc[mt][nt] =
              __builtin_amdgcn_mfma_f32_16x16x32_bf16(af[mt], bfv[nt], acc[mt][nt], 0, 0, 0);
    }
    __syncthreads();
  }

#pragma unroll
  for (int nt = 0; nt < 4; ++nt) {
    const int col = n0 + nt * 16 + l15;
    const float pbf = pb[col];
#pragma unroll
    for (int mt = 0; mt < 2; ++mt) {
#pragma unroll
      for (int r = 0; r < 4; ++r) {
        const int m = m0 + wave * 32 + mt * 16 + quad * 4 + r;
        out[(size_t)m * 256 + col] = acc[mt][nt][r] + pbf;
      }
    }
  }
}

extern "C" void kernel_launch(void* const* d_in, const int* in_sizes, int n_in,
                              void* d_out, int out_size, void* d_ws, size_t ws_size,
                              hipStream_t stream) {
  const float* x_in = (const float*)d_in[0];
  const float* qw1 = (const float*)d_in[1];
  const float* qw2 = (const float*)d_in[2];
  const float* qw3 = (const float*)d_in[3];
  const float* kw1 = (const float*)d_in[4];
  const float* kw2 = (const float*)d_in[5];
  const float* kw3 = (const float*)d_in[6];
  const float* vw1 = (const float*)d_in[7];
  const float* vw2 = (const float*)d_in[8];
  const float* vw3 = (const float*)d_in[9];
  const float* posw1 = (const float*)d_in[10];
  const float* posb1 = (const float*)d_in[11];
  const float* posw2 = (const float*)d_in[12];
  const float* posb2 = (const float*)d_in[13];
  const float* cw = (const float*)d_in[14];
  const float* cb = (const float*)d_in[15];
  const float* rs1 = (const float*)d_in[16];
  const float* rs2 = (const float*)d_in[17];
  const float* pw = (const float*)d_in[18];
  const float* pb = (const float*)d_in[19];

  char* ws = (char*)d_ws;
  const size_t SLOT = 67108864;  // one (2,256,256,256) bf16 image
  u16* S0 = (u16*)(ws);            // x2
  u16* S1 = (u16*)(ws + SLOT);     // v3
  u16* D0 = (u16*)d_out;           // q3 (border tiles only; dead before gemm)
  char* SM = ws + 2 * SLOT;
  float* G = (float*)(SM);              // 2*8*32*32 f32
  float* sqq = (float*)(SM + 65536);
  float* sqk = (float*)(SM + 67584);
  float* vsum = (float*)(SM + 69632);
  float* attn = (float*)(SM + 71680);
  u16* Mm = (u16*)(SM + 137216);
  float* Wc = (float*)(SM + 399360);    // composed weights [8][3][49] f32 (4.7KB)

  hipMemsetAsync(SM, 0, 71680, stream);

  compose_kernel<<<1, 64, 0, stream>>>(qw1, qw2, qw3, kw1, kw2, kw3,
                                       vw1, vw2, vw3, Wc);

  const dim3 tgrid(16, 32, 16);
  posemb_kernel<<<tgrid, 256, 0, stream>>>(x_in, S0, posw1, posb1, posw2, posb2);

  // Interior: fused q/k/v composed-7x7 + Gram + reductions (bx 1..14, by 1..30)
  qkv_fused_kernel<<<dim3(14, 30, 16), 256, 0, stream>>>(S0, S1, Wc, G, sqq, sqk, vsum);

  // Border: exact 3-stage path on 92 remapped tile positions
  const dim3 bgrid(92, 1, 16);
  chain3_kernel<1, 1><<<bgrid, 256, 0, stream>>>(S0, D0, qw1, qw2, qw3, sqq);
  kchain_gram_kernel<1><<<bgrid, 256, 0, stream>>>(S0, D0, kw1, kw2, kw3, G, sqk);
  chain3_kernel<2, 1><<<bgrid, 256, 0, stream>>>(S0, S1, vw1, vw2, vw3, vsum);

  attn_kernel<<<2, 256, 0, stream>>>(G, sqq, sqk, vsum, cw, cb, rs1, rs2, attn);
  mbuild_kernel<<<16, 256, 0, stream>>>(attn, pw, Mm);
  gemm_kernel<<<dim3(1024, 4), 256, 0, stream>>>(S1, Mm, pb, (float*)d_out);
}

// Round 9
// 872.223 us; speedup vs baseline: 2.1301x; 1.0074x over previous
//
#include <hip/hip_runtime.h>
#include <stdint.h>
#include <math.h>

// MS_MSA fused pipeline:
//   compose_kernel : Weff[h][chain] = w1*w2*w3 composed 7x7 stencil (fp32, ws)
//   posemb_kernel  : x2 = x + dw2(gelu(dw1(x)+b1))+b2   (2-stage tile fusion)
//   qkv_fused      : INTERIOR tiles — r1-verified kernel, byte-identical
//                    (joint composed-7x7 sweep, rolled iy loop, global s_load
//                    weights; all restructures r2-r8 were neutral or worse).
//   border_fused   : BORDER tiles (92 positions): ONE kernel runs the exact
//                    3-stage q,k,v chains sequentially off a single halo load
//                    (was 3 kernels x 3 halo loads + q3 HBM round-trip).
//                    q3/k3 stay in LDS; Gram MFMA + all reductions fused.
//   attn/mbuild    : softmax + fold proj_w*blockdiag(attn) -> M
//   gemm           : out = v3 @ M_b^T + proj_b  (bf16 MFMA, fp32 out)
// ws: S0=x2, S1=v3 (2 x 64MiB) + smalls + Wc(4.7KB) — layout == verified r1.

using u16 = unsigned short;
using u32 = unsigned int;

typedef __bf16 bf16x8_t __attribute__((ext_vector_type(8)));
typedef float f32x4_t __attribute__((ext_vector_type(4)));

__device__ __forceinline__ float bf2f(u16 v) {
  u32 u = ((u32)v) << 16;
  return __builtin_bit_cast(float, u);
}
__device__ __forceinline__ u16 f2bf(float f) {
  u32 u = __builtin_bit_cast(u32, f);
  u32 r = u + 0x7fffu + ((u >> 16) & 1u);  // RNE (finite inputs)
  return (u16)(r >> 16);
}
__device__ __forceinline__ void unpack8(uint4 u, float f[8]) {
  f[0] = bf2f((u16)(u.x & 0xffffu)); f[1] = bf2f((u16)(u.x >> 16));
  f[2] = bf2f((u16)(u.y & 0xffffu)); f[3] = bf2f((u16)(u.y >> 16));
  f[4] = bf2f((u16)(u.z & 0xffffu)); f[5] = bf2f((u16)(u.z >> 16));
  f[6] = bf2f((u16)(u.w & 0xffffu)); f[7] = bf2f((u16)(u.w >> 16));
}
__device__ __forceinline__ uint4 pack8(const u16 o[8]) {
  uint4 v;
  v.x = (u32)o[0] | ((u32)o[1] << 16);
  v.y = (u32)o[2] | ((u32)o[3] << 16);
  v.z = (u32)o[4] | ((u32)o[5] << 16);
  v.w = (u32)o[6] | ((u32)o[7] << 16);
  return v;
}

// ---------------------------------------------------------------------------
// compose: Weff = w1 (*) w2 (*) w3 (kernel-array convolution; correlation
// offsets add). Wc[h][c][dy*7+dx], c: 0=q,1=k,2=v. 24 active threads.
__global__ __launch_bounds__(64) void compose_kernel(
    const float* __restrict__ qw1, const float* __restrict__ qw2,
    const float* __restrict__ qw3, const float* __restrict__ kw1,
    const float* __restrict__ kw2, const float* __restrict__ kw3,
    const float* __restrict__ vw1, const float* __restrict__ vw2,
    const float* __restrict__ vw3, float* __restrict__ Wc) {
  const int t = threadIdx.x;
  if (t >= 24) return;
  const int h = t / 3, c = t % 3;
  const float* w1 = (c == 0 ? qw1 : c == 1 ? kw1 : vw1) + h * 9;
  const float* w2 = (c == 0 ? qw2 : c == 1 ? kw2 : vw2) + h * 9;
  const float* w3 = (c == 0 ? qw3 : c == 1 ? kw3 : vw3) + h * 9;
  float w12[25];
  for (int i = 0; i < 25; ++i) w12[i] = 0.f;
  for (int ky = 0; ky < 3; ++ky)
    for (int kx = 0; kx < 3; ++kx)
      for (int ly = 0; ly < 3; ++ly)
        for (int lx = 0; lx < 3; ++lx)
          w12[(ky + ly) * 5 + kx + lx] += w2[ky * 3 + kx] * w1[ly * 3 + lx];
  float we[49];
  for (int i = 0; i < 49; ++i) we[i] = 0.f;
  for (int my = 0; my < 3; ++my)
    for (int mx = 0; mx < 3; ++mx)
      for (int ey = 0; ey < 5; ++ey)
        for (int ex = 0; ex < 5; ++ex)
          we[(my + ey) * 7 + mx + ex] += w3[my * 3 + mx] * w12[ey * 5 + ex];
  float* dst = Wc + (h * 3 + c) * 49;
  for (int i = 0; i < 49; ++i) dst[i] = we[i];
}

// ---------------------------------------------------------------------------
// posemb: 2-stage fused, per-channel weights, fp32 input, gelu, residual.
__global__ __launch_bounds__(256) void posemb_kernel(
    const float* __restrict__ xin, u16* __restrict__ x2,
    const float* __restrict__ w1g, const float* __restrict__ b1g,
    const float* __restrict__ w2g, const float* __restrict__ b2g) {
  const int t = threadIdx.x;
  const int o = t & 3;
  const int bz = blockIdx.z;
  const int cg = bz & 7;
  const int b = bz >> 3;
  const int x0 = blockIdx.x * 16;
  const int y0 = blockIdx.y * 8;
  const int c0 = cg * 32 + o * 8;

  __shared__ __align__(16) u16 Abuf[240 * 32];
  __shared__ __align__(16) u16 Bbuf[180 * 32];

  for (int i = t; i < 240 * 4; i += 256) {
    const int px = i >> 2, oo = i & 3;
    const int lx = px % 20, ly = px / 20;
    const int gx = x0 - 2 + lx, gy = y0 - 2 + ly;
    u16 ov[8];
    if (gx >= 0 && gx < 256 && gy >= 0 && gy < 256) {
      const float* p = xin + ((size_t)((b << 16) + (gy << 8) + gx)) * 256 + cg * 32 + oo * 8;
      const float4 r0 = *reinterpret_cast<const float4*>(p);
      const float4 r1 = *reinterpret_cast<const float4*>(p + 4);
      ov[0] = f2bf(r0.x); ov[1] = f2bf(r0.y); ov[2] = f2bf(r0.z); ov[3] = f2bf(r0.w);
      ov[4] = f2bf(r1.x); ov[5] = f2bf(r1.y); ov[6] = f2bf(r1.z); ov[7] = f2bf(r1.w);
    } else {
#pragma unroll
      for (int j = 0; j < 8; ++j) ov[j] = 0;
    }
    *reinterpret_cast<uint4*>(Abuf + px * 32 + oo * 8) = pack8(ov);
  }
  __syncthreads();

  {
    float w[72], bi[8];
#pragma unroll
    for (int j = 0; j < 8; ++j) {
#pragma unroll
      for (int k = 0; k < 9; ++k) w[j * 9 + k] = w1g[(c0 + j) * 9 + k];
      bi[j] = b1g[c0 + j];
    }
    for (int i = t; i < 180 * 4; i += 256) {
      const int px = i >> 2;
      const int sx = px % 18, sy = px / 18;
      const int gx = x0 - 1 + sx, gy = y0 - 1 + sy;
      const bool inb = (gx >= 0 && gx < 256 && gy >= 0 && gy < 256);
      float a[8];
#pragma unroll
      for (int j = 0; j < 8; ++j) a[j] = bi[j];
#pragma unroll
      for (int ky = 0; ky < 3; ++ky)
#pragma unroll
        for (int kx = 0; kx < 3; ++kx) {
          float f[8];
          unpack8(*reinterpret_cast<const uint4*>(
                      Abuf + ((sy + ky) * 20 + sx + kx) * 32 + o * 8), f);
#pragma unroll
          for (int j = 0; j < 8; ++j) a[j] = fmaf(w[j * 9 + ky * 3 + kx], f[j], a[j]);
        }
      u16 ov[8];
#pragma unroll
      for (int j = 0; j < 8; ++j) {
        const float g = 0.5f * a[j] * (1.0f + erff(a[j] * 0.70710678118654752f));
        ov[j] = inb ? f2bf(g) : (u16)0;
      }
      *reinterpret_cast<uint4*>(Bbuf + px * 32 + o * 8) = pack8(ov);
    }
  }
  __syncthreads();

  {
    float w[72], bi[8];
#pragma unroll
    for (int j = 0; j < 8; ++j) {
#pragma unroll
      for (int k = 0; k < 9; ++k) w[j * 9 + k] = w2g[(c0 + j) * 9 + k];
      bi[j] = b2g[c0 + j];
    }
    for (int i = t; i < 128 * 4; i += 256) {
      const int px = i >> 2;
      const int sx = px & 15, sy = px >> 4;
      float a[8];
#pragma unroll
      for (int j = 0; j < 8; ++j) a[j] = bi[j];
#pragma unroll
      for (int ky = 0; ky < 3; ++ky)
#pragma unroll
        for (int kx = 0; kx < 3; ++kx) {
          float f[8];
          unpack8(*reinterpret_cast<const uint4*>(
                      Bbuf + ((sy + ky) * 18 + sx + kx) * 32 + o * 8), f);
#pragma unroll
          for (int j = 0; j < 8; ++j) a[j] = fmaf(w[j * 9 + ky * 3 + kx], f[j], a[j]);
        }
      float xr[8];
      unpack8(*reinterpret_cast<const uint4*>(
                  Abuf + ((sy + 2) * 20 + sx + 2) * 32 + o * 8), xr);
      u16 ov[8];
#pragma unroll
      for (int j = 0; j < 8; ++j) ov[j] = f2bf(a[j] + xr[j]);
      u16* dst = x2 + ((size_t)((b << 16) + ((y0 + sy) << 8) + x0 + sx)) * 256 + cg * 32 + o * 8;
      *reinterpret_cast<uint4*>(dst) = pack8(ov);
    }
  }
}

// ---------------------------------------------------------------------------
// qkv_fused: interior tiles only (bx 1..14, by 1..30) — r1-verified kernel.
__global__ __launch_bounds__(256) void qkv_fused_kernel(
    const u16* __restrict__ x2, u16* __restrict__ v3out,
    const float* __restrict__ Wc, float* __restrict__ G,
    float* __restrict__ sqq, float* __restrict__ sqk,
    float* __restrict__ vsum) {
  const int t = threadIdx.x;
  const int o = t & 3;
  const int sx = (t >> 2) & 15;
  const int yg = t >> 6;
  const int bz = blockIdx.z;
  const int h = bz & 7;
  const int b = bz >> 3;
  const int x0 = (blockIdx.x + 1) * 16;
  const int y0 = (blockIdx.y + 1) * 8;

  __shared__ __align__(16) u16 Abuf[308 * 32];  // halo 22x14; later K3s/Q3s
  __shared__ float rbuf[96];
  if (t < 96) rbuf[t] = 0.f;

  // P0: load halo (interior -> no bounds checks)
  for (int i = t; i < 308 * 4; i += 256) {
    const int px = i >> 2, oo = i & 3;
    const int lx = px % 22, ly = px / 22;
    const int gx = x0 - 3 + lx, gy = y0 - 3 + ly;
    *reinterpret_cast<uint4*>(Abuf + px * 32 + oo * 8) =
        *reinterpret_cast<const uint4*>(
            x2 + ((size_t)((b << 16) + (gy << 8) + gx)) * 256 + h * 32 + oo * 8);
  }
  __syncthreads();

  const float* Wq = Wc + (h * 3 + 0) * 49;
  const float* Wk = Wc + (h * 3 + 1) * 49;
  const float* Wv = Wc + (h * 3 + 2) * 49;

  float aq[2][8], ak[2][8], av2[2][8];
#pragma unroll
  for (int r = 0; r < 2; ++r)
#pragma unroll
    for (int j = 0; j < 8; ++j) { aq[r][j] = 0.f; ak[r][j] = 0.f; av2[r][j] = 0.f; }

  const int ty0 = yg * 2;
  const u16* Arow0 = Abuf + (ty0 * 22 + sx) * 32 + o * 8;

  // iy = 0: serves ry=0 only (dy=0)
  {
    const u16* Ar = Arow0;
#pragma unroll
    for (int jx = 0; jx < 7; ++jx) {
      float f[8];
      unpack8(*reinterpret_cast<const uint4*>(Ar + jx * 32), f);
      const float wq = Wq[jx], wk = Wk[jx], wv = Wv[jx];
#pragma unroll
      for (int j = 0; j < 8; ++j) {
        aq[0][j] = fmaf(wq, f[j], aq[0][j]);
        ak[0][j] = fmaf(wk, f[j], ak[0][j]);
        av2[0][j] = fmaf(wv, f[j], av2[0][j]);
      }
    }
  }
  // iy = 1..6: serves ry=0 (dy=iy) and ry=1 (dy=iy-1). Rolled (unroll -> spill).
#pragma unroll 1
  for (int iy = 1; iy <= 6; ++iy) {
    const u16* Ar = Arow0 + iy * (22 * 32);
    const float* wq0 = Wq + iy * 7;
    const float* wk0 = Wk + iy * 7;
    const float* wv0 = Wv + iy * 7;
#pragma unroll
    for (int jx = 0; jx < 7; ++jx) {
      float f[8];
      unpack8(*reinterpret_cast<const uint4*>(Ar + jx * 32), f);
      float w;
      w = wq0[jx];
#pragma unroll
      for (int j = 0; j < 8; ++j) aq[0][j] = fmaf(w, f[j], aq[0][j]);
      w = wq0[jx - 7];
#pragma unroll
      for (int j = 0; j < 8; ++j) aq[1][j] = fmaf(w, f[j], aq[1][j]);
      w = wk0[jx];
#pragma unroll
      for (int j = 0; j < 8; ++j) ak[0][j] = fmaf(w, f[j], ak[0][j]);
      w = wk0[jx - 7];
#pragma unroll
      for (int j = 0; j < 8; ++j) ak[1][j] = fmaf(w, f[j], ak[1][j]);
      w = wv0[jx];
#pragma unroll
      for (int j = 0; j < 8; ++j) av2[0][j] = fmaf(w, f[j], av2[0][j]);
      w = wv0[jx - 7];
#pragma unroll
      for (int j = 0; j < 8; ++j) av2[1][j] = fmaf(w, f[j], av2[1][j]);
    }
  }
  // iy = 7: serves ry=1 only (dy=6)
  {
    const u16* Ar = Arow0 + 7 * (22 * 32);
#pragma unroll
    for (int jx = 0; jx < 7; ++jx) {
      float f[8];
      unpack8(*reinterpret_cast<const uint4*>(Ar + jx * 32), f);
      const float wq = Wq[42 + jx], wk = Wk[42 + jx], wv = Wv[42 + jx];
#pragma unroll
      for (int j = 0; j < 8; ++j) {
        aq[1][j] = fmaf(wq, f[j], aq[1][j]);
        ak[1][j] = fmaf(wk, f[j], ak[1][j]);
        av2[1][j] = fmaf(wv, f[j], av2[1][j]);
      }
    }
  }

  __syncthreads();  // all Abuf reads done -> safe to alias staging into it

  u16* K3s = Abuf;             // [32][132]
  u16* Q3s = Abuf + 32 * 132;  // [32][132]

  float rq[8], rk[8], rv[8];
#pragma unroll
  for (int j = 0; j < 8; ++j) { rq[j] = 0.f; rk[j] = 0.f; rv[j] = 0.f; }
#pragma unroll
  for (int ry = 0; ry < 2; ++ry) {
    const int px = (ty0 + ry) * 16 + sx;
    u16 ov[8];
#pragma unroll
    for (int j = 0; j < 8; ++j) {
      const u16 qb = f2bf(aq[ry][j]);
      Q3s[(o * 8 + j) * 132 + px] = qb;
      const float qf = bf2f(qb);
      rq[j] = fmaf(qf, qf, rq[j]);
      const u16 kb = f2bf(ak[ry][j]);
      K3s[(o * 8 + j) * 132 + px] = kb;
      const float kf = bf2f(kb);
      rk[j] = fmaf(kf, kf, rk[j]);
      ov[j] = f2bf(av2[ry][j]);
      rv[j] += bf2f(ov[j]);
    }
    u16* dst = v3out + ((size_t)((b << 16) + ((y0 + ty0 + ry) << 8) + x0 + sx)) * 256 + h * 32 + o * 8;
    *reinterpret_cast<uint4*>(dst) = pack8(ov);
  }
#pragma unroll
  for (int j = 0; j < 8; ++j) {
    atomicAdd(&rbuf[o * 8 + j], rq[j]);
    atomicAdd(&rbuf[32 + o * 8 + j], rk[j]);
    atomicAdd(&rbuf[64 + o * 8 + j], rv[j]);
  }
  __syncthreads();

  // Gram MFMA: wave -> 16x16 quadrant, K=128 (whole tile)
  const int wave = t >> 6;
  const int lane = t & 63;
  const int quad = lane >> 4;
  const int l15 = lane & 15;
  const int d0 = (wave & 1) * 16;
  const int e0 = (wave >> 1) * 16;
  f32x4_t acc = {0.f, 0.f, 0.f, 0.f};
#pragma unroll
  for (int kb = 0; kb < 4; ++kb) {
    const bf16x8_t avf = *reinterpret_cast<const bf16x8_t*>(
        &K3s[(d0 + l15) * 132 + kb * 32 + quad * 8]);
    const bf16x8_t bvf = *reinterpret_cast<const bf16x8_t*>(
        &Q3s[(e0 + l15) * 132 + kb * 32 + quad * 8]);
    acc = __builtin_amdgcn_mfma_f32_16x16x32_bf16(avf, bvf, acc, 0, 0, 0);
  }
  float* Gp = G + (size_t)((b * 8 + h) * 32) * 32;
#pragma unroll
  for (int r = 0; r < 4; ++r)
    atomicAdd(&Gp[(d0 + quad * 4 + r) * 32 + e0 + l15], acc[r]);

  if (t < 32) atomicAdd(&sqq[b * 256 + h * 32 + t], rbuf[t]);
  else if (t < 64) atomicAdd(&sqk[b * 256 + h * 32 + (t - 32)], rbuf[t]);
  else if (t < 96) atomicAdd(&vsum[b * 256 + h * 32 + (t - 64)], rbuf[t]);
}

// ---------------------------------------------------------------------------
// Border block-index remap: 92 positions.
__device__ __forceinline__ void border_map(int bi, int& bx, int& by) {
  if (bi < 16) { bx = bi; by = 0; }
  else if (bi < 32) { bx = bi - 16; by = 31; }
  else { const int e = bi - 32; by = 1 + (e >> 1); bx = (e & 1) * 15; }
}

// ---------------------------------------------------------------------------
// border_fused: exact 3-stage path for q,k,v in ONE kernel off a single halo
// load. q3->Q3s, k3->K3s (LDS, bit-identical to the old global round-trip),
// v3->HBM. s2 lives in Cbuf (halo stays live across chains). Gram MFMA +
// sqq/sqk/vsum at the end. Grid (92,1,16). LDS 63.9KB -> 2 blocks/CU.
__global__ __launch_bounds__(256) void border_fused_kernel(
    const u16* __restrict__ in, u16* __restrict__ v3out,
    const float* __restrict__ qw1, const float* __restrict__ qw2,
    const float* __restrict__ qw3, const float* __restrict__ kw1,
    const float* __restrict__ kw2, const float* __restrict__ kw3,
    const float* __restrict__ vw1, const float* __restrict__ vw2,
    const float* __restrict__ vw3, float* __restrict__ G,
    float* __restrict__ sqq, float* __restrict__ sqk,
    float* __restrict__ vsum) {
  const int t = threadIdx.x;
  const int o = t & 3;
  const int bz = blockIdx.z;
  const int h = bz & 7;
  const int b = bz >> 3;
  int bx, by;
  border_map(blockIdx.x, bx, by);
  const int x0 = bx * 16;
  const int y0 = by * 8;

  __shared__ __align__(16) u16 Halo[308 * 32];  // 22x14, live all 3 chains
  __shared__ __align__(16) u16 Bbuf[240 * 32];  // s1 20x12
  __shared__ __align__(16) u16 Cbuf[180 * 32];  // s2 18x10
  __shared__ __align__(16) u16 K3s[32 * 132];
  __shared__ __align__(16) u16 Q3s[32 * 132];
  __shared__ float rbuf[96];
  if (t < 96) rbuf[t] = 0.f;

  // halo load (bounds-checked, zero outside image)
  for (int i = t; i < 308 * 4; i += 256) {
    const int px = i >> 2, oo = i & 3;
    const int lx = px % 22, ly = px / 22;
    const int gx = x0 - 3 + lx, gy = y0 - 3 + ly;
    uint4 v = {0, 0, 0, 0};
    if (gx >= 0 && gx < 256 && gy >= 0 && gy < 256)
      v = *reinterpret_cast<const uint4*>(
          in + ((size_t)((b << 16) + (gy << 8) + gx)) * 256 + h * 32 + oo * 8);
    *reinterpret_cast<uint4*>(Halo + px * 32 + oo * 8) = v;
  }
  __syncthreads();

#pragma unroll 1
  for (int c = 0; c < 3; ++c) {
    const float* w1g = (c == 0 ? qw1 : c == 1 ? kw1 : vw1);
    const float* w2g = (c == 0 ? qw2 : c == 1 ? kw2 : vw2);
    const float* w3g = (c == 0 ? qw3 : c == 1 ? kw3 : vw3);
    float w1[9], w2[9], w3[9];
#pragma unroll
    for (int k = 0; k < 9; ++k) {
      w1[k] = w1g[h * 9 + k];
      w2[k] = w2g[h * 9 + k];
      w3[k] = w3g[h * 9 + k];
    }

    // stage1: s1 over 20x12 — zero outside image
    for (int i = t; i < 240 * 4; i += 256) {
      const int px = i >> 2;
      const int sx = px % 20, sy = px / 20;
      const int gx = x0 - 2 + sx, gy = y0 - 2 + sy;
      const bool inb = (gx >= 0 && gx < 256 && gy >= 0 && gy < 256);
      float a[8] = {0, 0, 0, 0, 0, 0, 0, 0};
#pragma unroll
      for (int ky = 0; ky < 3; ++ky)
#pragma unroll
        for (int kx = 0; kx < 3; ++kx) {
          float f[8];
          unpack8(*reinterpret_cast<const uint4*>(
                      Halo + ((sy + ky) * 22 + sx + kx) * 32 + o * 8), f);
#pragma unroll
          for (int j = 0; j < 8; ++j) a[j] = fmaf(w1[ky * 3 + kx], f[j], a[j]);
        }
      u16 ov[8];
#pragma unroll
      for (int j = 0; j < 8; ++j) ov[j] = inb ? f2bf(a[j]) : (u16)0;
      *reinterpret_cast<uint4*>(Bbuf + px * 32 + o * 8) = pack8(ov);
    }
    __syncthreads();

    // stage2: s2 over 18x10 -> Cbuf — zero outside image
    for (int i = t; i < 180 * 4; i += 256) {
      const int px = i >> 2;
      const int sx = px % 18, sy = px / 18;
      const int gx = x0 - 1 + sx, gy = y0 - 1 + sy;
      const bool inb = (gx >= 0 && gx < 256 && gy >= 0 && gy < 256);
      float a[8] = {0, 0, 0, 0, 0, 0, 0, 0};
#pragma unroll
      for (int ky = 0; ky < 3; ++ky)
#pragma unroll
        for (int kx = 0; kx < 3; ++kx) {
          float f[8];
          unpack8(*reinterpret_cast<const uint4*>(
                      Bbuf + ((sy + ky) * 20 + sx + kx) * 32 + o * 8), f);
#pragma unroll
          for (int j = 0; j < 8; ++j) a[j] = fmaf(w2[ky * 3 + kx], f[j], a[j]);
        }
      u16 ov[8];
#pragma unroll
      for (int j = 0; j < 8; ++j) ov[j] = inb ? f2bf(a[j]) : (u16)0;
      *reinterpret_cast<uint4*>(Cbuf + px * 32 + o * 8) = pack8(ov);
    }
    __syncthreads();

    // stage3: out over 16x8 -> {Q3s | K3s | v3out} + per-channel reduction
    float racc[8] = {0, 0, 0, 0, 0, 0, 0, 0};
    for (int i = t; i < 128 * 4; i += 256) {
      const int px = i >> 2;
      const int sx = px & 15, sy = px >> 4;
      float a[8] = {0, 0, 0, 0, 0, 0, 0, 0};
#pragma unroll
      for (int ky = 0; ky < 3; ++ky)
#pragma unroll
        for (int kx = 0; kx < 3; ++kx) {
          float f[8];
          unpack8(*reinterpret_cast<const uint4*>(
                      Cbuf + ((sy + ky) * 18 + sx + kx) * 32 + o * 8), f);
#pragma unroll
          for (int j = 0; j < 8; ++j) a[j] = fmaf(w3[ky * 3 + kx], f[j], a[j]);
        }
      u16 ov[8];
#pragma unroll
      for (int j = 0; j < 8; ++j) ov[j] = f2bf(a[j]);
      if (c == 0) {
#pragma unroll
        for (int j = 0; j < 8; ++j) {
          Q3s[(o * 8 + j) * 132 + px] = ov[j];
          const float f = bf2f(ov[j]);
          racc[j] = fmaf(f, f, racc[j]);
        }
      } else if (c == 1) {
#pragma unroll
        for (int j = 0; j < 8; ++j) {
          K3s[(o * 8 + j) * 132 + px] = ov[j];
          const float f = bf2f(ov[j]);
          racc[j] = fmaf(f, f, racc[j]);
        }
      } else {
#pragma unroll
        for (int j = 0; j < 8; ++j) racc[j] += bf2f(ov[j]);
        u16* dst = v3out + ((size_t)((b << 16) + ((y0 + sy) << 8) + x0 + sx)) * 256 + h * 32 + o * 8;
        *reinterpret_cast<uint4*>(dst) = pack8(ov);
      }
    }
    __syncthreads();
#pragma unroll
    for (int j = 0; j < 8; ++j) atomicAdd(&rbuf[c * 32 + o * 8 + j], racc[j]);
    __syncthreads();
  }

  // Gram MFMA: wave -> 16x16 quadrant, K=128 (whole tile)
  const int wave = t >> 6;
  const int lane = t & 63;
  const int quad = lane >> 4;
  const int l15 = lane & 15;
  const int d0 = (wave & 1) * 16;
  const int e0 = (wave >> 1) * 16;
  f32x4_t acc = {0.f, 0.f, 0.f, 0.f};
#pragma unroll
  for (int kb = 0; kb < 4; ++kb) {
    const bf16x8_t av = *reinterpret_cast<const bf16x8_t*>(
        &K3s[(d0 + l15) * 132 + kb * 32 + quad * 8]);
    const bf16x8_t bv = *reinterpret_cast<const bf16x8_t*>(
        &Q3s[(e0 + l15) * 132 + kb * 32 + quad * 8]);
    acc = __builtin_amdgcn_mfma_f32_16x16x32_bf16(av, bv, acc, 0, 0, 0);
  }
  float* Gp = G + (size_t)((b * 8 + h) * 32) * 32;
#pragma unroll
  for (int r = 0; r < 4; ++r)
    atomicAdd(&Gp[(d0 + quad * 4 + r) * 32 + e0 + l15], acc[r]);

  if (t < 32) atomicAdd(&sqq[b * 256 + h * 32 + t], rbuf[t]);
  else if (t < 64) atomicAdd(&sqk[b * 256 + h * 32 + (t - 32)], rbuf[t]);
  else if (t < 96) atomicAdd(&vsum[b * 256 + h * 32 + (t - 64)], rbuf[t]);
}

// ---------------------------------------------------------------------------
// attn finalize: normalize Gram, conv1d diag, softmax.
__global__ __launch_bounds__(256) void attn_kernel(
    const float* __restrict__ G, const float* __restrict__ sqq,
    const float* __restrict__ sqk, const float* __restrict__ vsum,
    const float* __restrict__ cw, const float* __restrict__ cb,
    const float* __restrict__ rs1, const float* __restrict__ rs2,
    float* __restrict__ attn) {
  const int b = blockIdx.x;
  const int t = threadIdx.x;
  const int h = t >> 5;
  const int d = t & 31;
  __shared__ float vm[8][34];
  __shared__ float nq[256];
  vm[h][d + 1] = vsum[b * 256 + t] * (1.0f / 65536.0f);
  if (t < 8) { vm[t][0] = 0.f; vm[t][33] = 0.f; }
  nq[t] = fmaxf(sqrtf(sqq[b * 256 + t]), 1e-12f);
  __syncthreads();

  float av = cb[h];
#pragma unroll
  for (int i = 0; i < 8; ++i)
#pragma unroll
    for (int tau = 0; tau < 3; ++tau)
      av = fmaf(cw[h * 24 + i * 3 + tau], vm[i][d + tau], av);

  const float nk = fmaxf(sqrtf(sqk[b * 256 + t]), 1e-12f);
  const float rsc = rs1[h];
  const float rsc2 = rs2[h];
  const float* Gp = G + (size_t)((b * 8 + h) * 32 + d) * 32;
  float L[32];
#pragma unroll
  for (int e = 0; e < 32; ++e) {
    float l = Gp[e] * rsc / (nk * nq[h * 32 + e]);
    if (e == d) l += av * rsc2;
    L[e] = l;
  }
  float mx = L[0];
#pragma unroll
  for (int e = 1; e < 32; ++e) mx = fmaxf(mx, L[e]);
  float s = 0.f;
#pragma unroll
  for (int e = 0; e < 32; ++e) {
    L[e] = expf(L[e] - mx);
    s += L[e];
  }
  const float inv = 1.0f / s;
  float* Ap = attn + (size_t)((b * 8 + h) * 32 + d) * 32;
#pragma unroll
  for (int e = 0; e < 32; ++e) Ap[e] = L[e] * inv;
}

// M_b[c'][h*32+e] = sum_d proj_w[c'][h*32+d] * attn[b,h,d,e]  (bf16)
__global__ __launch_bounds__(256) void mbuild_kernel(
    const float* __restrict__ attn, const float* __restrict__ pw,
    u16* __restrict__ M) {
  const int bid = blockIdx.x;
  const int b = bid >> 3;
  const int h = bid & 7;
  const int t = threadIdx.x;
  __shared__ float at[32][33];
#pragma unroll
  for (int i = 0; i < 4; ++i) {
    const int idx = t * 4 + i;
    at[idx >> 5][idx & 31] = attn[(size_t)(b * 8 + h) * 1024 + idx];
  }
  __syncthreads();
  float pwf[32];
#pragma unroll
  for (int dd = 0; dd < 32; ++dd) pwf[dd] = pw[(size_t)t * 256 + h * 32 + dd];
  u16* Mp = M + (size_t)b * 65536 + (size_t)t * 256 + h * 32;
#pragma unroll
  for (int e = 0; e < 32; ++e) {
    float s = 0.f;
#pragma unroll
    for (int dd = 0; dd < 32; ++dd) s = fmaf(pwf[dd], at[dd][e], s);
    Mp[e] = f2bf(s);
  }
}

// out[m][c'] = sum_k v3[m][k] * M_b[c'][k] + proj_b[c'].  128x64 tile, fp32 out.
__global__ __launch_bounds__(256) void gemm_kernel(
    const u16* __restrict__ V, const u16* __restrict__ Mm,
    const float* __restrict__ pb, float* __restrict__ out) {
  const int m0 = blockIdx.x * 128;
  const int n0 = blockIdx.y * 64;
  const int b = m0 >> 16;
  const u16* Mb = Mm + (size_t)b * 65536;

  __shared__ __align__(16) u16 As[128][72];
  __shared__ __align__(16) u16 Bs[64][72];

  const int t = threadIdx.x;
  const int wave = t >> 6;
  const int lane = t & 63;
  const int quad = lane >> 4;
  const int l15 = lane & 15;

  f32x4_t acc[2][4];
#pragma unroll
  for (int mt = 0; mt < 2; ++mt)
#pragma unroll
    for (int nt = 0; nt < 4; ++nt) acc[mt][nt] = {0.f, 0.f, 0.f, 0.f};

  for (int k0 = 0; k0 < 256; k0 += 64) {
#pragma unroll
    for (int i = 0; i < 4; ++i) {
      const int id = t + 256 * i;
      const int row = id >> 3;
      const int c8 = id & 7;
      *reinterpret_cast<uint4*>(&As[row][c8 * 8]) = *reinterpret_cast<const uint4*>(
          &V[(size_t)(m0 + row) * 256 + k0 + c8 * 8]);
    }
#pragma unroll
    for (int i = 0; i < 2; ++i) {
      const int id = t + 256 * i;
      const int row = id >> 3;
      const int c8 = id & 7;
      *reinterpret_cast<uint4*>(&Bs[row][c8 * 8]) = *reinterpret_cast<const uint4*>(
          &Mb[(size_t)(n0 + row) * 256 + k0 + c8 * 8]);
    }
    __syncthreads();
#pragma unroll
    for (int ks = 0; ks < 2; ++ks) {
      bf16x8_t af[2], bfv[4];
#pragma unroll
      for (int mt = 0; mt < 2; ++mt)
        af[mt] = *reinterpret_cast<const bf16x8_t*>(
            &As[wave * 32 + mt * 16 + l15][ks * 32 + quad * 8]);
#pragma unroll
      for (int nt = 0; nt < 4; ++nt)
        bfv[nt] = *reinterpret_cast<const bf16x8_t*>(
            &Bs[nt * 16 + l15][ks * 32 + quad * 8]);
#pragma unroll
      for (int mt = 0; mt < 2; ++mt)
#pragma unroll
        for (int nt = 0; nt < 4; ++nt)
          acc[mt][nt] =
              __builtin_amdgcn_mfma_f32_16x16x32_bf16(af[mt], bfv[nt], acc[mt][nt], 0, 0, 0);
    }
    __syncthreads();
  }

#pragma unroll
  for (int nt = 0; nt < 4; ++nt) {
    const int col = n0 + nt * 16 + l15;
    const float pbf = pb[col];
#pragma unroll
    for (int mt = 0; mt < 2; ++mt) {
#pragma unroll
      for (int r = 0; r < 4; ++r) {
        const int m = m0 + wave * 32 + mt * 16 + quad * 4 + r;
        out[(size_t)m * 256 + col] = acc[mt][nt][r] + pbf;
      }
    }
  }
}

extern "C" void kernel_launch(void* const* d_in, const int* in_sizes, int n_in,
                              void* d_out, int out_size, void* d_ws, size_t ws_size,
                              hipStream_t stream) {
  const float* x_in = (const float*)d_in[0];
  const float* qw1 = (const float*)d_in[1];
  const float* qw2 = (const float*)d_in[2];
  const float* qw3 = (const float*)d_in[3];
  const float* kw1 = (const float*)d_in[4];
  const float* kw2 = (const float*)d_in[5];
  const float* kw3 = (const float*)d_in[6];
  const float* vw1 = (const float*)d_in[7];
  const float* vw2 = (const float*)d_in[8];
  const float* vw3 = (const float*)d_in[9];
  const float* posw1 = (const float*)d_in[10];
  const float* posb1 = (const float*)d_in[11];
  const float* posw2 = (const float*)d_in[12];
  const float* posb2 = (const float*)d_in[13];
  const float* cw = (const float*)d_in[14];
  const float* cb = (const float*)d_in[15];
  const float* rs1 = (const float*)d_in[16];
  const float* rs2 = (const float*)d_in[17];
  const float* pw = (const float*)d_in[18];
  const float* pb = (const float*)d_in[19];

  char* ws = (char*)d_ws;
  const size_t SLOT = 67108864;  // one (2,256,256,256) bf16 image
  u16* S0 = (u16*)(ws);            // x2
  u16* S1 = (u16*)(ws + SLOT);     // v3
  char* SM = ws + 2 * SLOT;
  float* G = (float*)(SM);              // 2*8*32*32 f32
  float* sqq = (float*)(SM + 65536);
  float* sqk = (float*)(SM + 67584);
  float* vsum = (float*)(SM + 69632);
  float* attn = (float*)(SM + 71680);
  u16* Mm = (u16*)(SM + 137216);
  float* Wc = (float*)(SM + 399360);    // composed weights [8][3][49] f32 (4.7KB)

  hipMemsetAsync(SM, 0, 71680, stream);

  compose_kernel<<<1, 64, 0, stream>>>(qw1, qw2, qw3, kw1, kw2, kw3,
                                       vw1, vw2, vw3, Wc);

  const dim3 tgrid(16, 32, 16);
  posemb_kernel<<<tgrid, 256, 0, stream>>>(x_in, S0, posw1, posb1, posw2, posb2);

  // Interior: fused q/k/v composed-7x7 + Gram + reductions (bx 1..14, by 1..30)
  qkv_fused_kernel<<<dim3(14, 30, 16), 256, 0, stream>>>(S0, S1, Wc, G, sqq, sqk, vsum);

  // Border: exact 3-stage q,k,v in one kernel (92 remapped tile positions)
  border_fused_kernel<<<dim3(92, 1, 16), 256, 0, stream>>>(
      S0, S1, qw1, qw2, qw3, kw1, kw2, kw3, vw1, vw2, vw3, G, sqq, sqk, vsum);

  attn_kernel<<<2, 256, 0, stream>>>(G, sqq, sqk, vsum, cw, cb, rs1, rs2, attn);
  mbuild_kernel<<<16, 256, 0, stream>>>(attn, pw, Mm);
  gemm_kernel<<<dim3(1024, 4), 256, 0, stream>>>(S1, Mm, pb, (float*)d_out);
}